// Round 10
// baseline (1291.083 us; speedup 1.0000x reference)
//
#include <hip/hip_runtime.h>
#include <hip/hip_bf16.h>
#include <hip/hip_cooperative_groups.h>

namespace cg = cooperative_groups;

// ZINC GINE inner, round 22.
// r21: 1002.6us best; profile flat, k_mlp top (50us, lockstep latency-bound).
// r22: fuse BN into node MLP via hipLaunchCooperativeKernel grid sync:
// k_mlpbn/k_mlpbn1 keep z in REGISTERS (bf16-packed, zreg[4][32], static
// indexing), accumulate stats, grid.sync(), then BN+relu+residual -> h.
// Deletes k_bn (3 launches) and z write+read (~102MB/layer x3).
// Layer 4 keeps plain k_mlp (poolbn consumes raw z). Gathers = r21 batch-of-4.

#define BNEPS 1e-5f
#define LDA 136   // 128 + 8 shorts pad
#define SCAN_NB 240

typedef __attribute__((ext_vector_type(8))) short bf16x8;
typedef __attribute__((ext_vector_type(8))) unsigned short u16x8;
typedef __attribute__((ext_vector_type(4))) float f32x4;

__device__ inline short f2bf(float f) {
    __hip_bfloat16 h = __float2bfloat16(f);
    return *reinterpret_cast<short*>(&h);
}
__device__ inline unsigned short f2bfu(float f) {
    __hip_bfloat16 h = __float2bfloat16(f);
    return *reinterpret_cast<unsigned short*>(&h);
}
__device__ inline float bf2f(unsigned short u) {
    union { unsigned int i; float f; } v; v.i = ((unsigned int)u) << 16; return v.f;
}

// Fragment-ordered index for a [128][128] W^T (n = out col, k = in dim):
// frag (nt,kt) = ((n>>4)*4 + (k>>5)); lane = ((k>>3)&3)*16 + (n&15); j = k&7.
// Consumer: frag(nt,kt) for lane L is 16B at W[((nt*4+kt)*64 + L)*8].

// ---------------- prep: 10 f32 [128,128] weights -> bf16 W^T frag-ordered ----------------
__global__ __launch_bounds__(256) void k_prep(
    const float* __restrict__ m1W2, const float* __restrict__ beW2,
    const float* __restrict__ mW1, const float* __restrict__ mW2,
    short* __restrict__ out)
{
    __shared__ float tileS[64][65];
    int b = blockIdx.x, mat = b >> 2, t = b & 3;
    const float* Wsrc;
    if (mat == 0) Wsrc = m1W2;
    else {
        int l = (mat - 1) / 3, which = (mat - 1) % 3;
        Wsrc = (which == 0) ? beW2 + (size_t)l * 16384
             : (which == 1) ? mW1 + (size_t)l * 16384
             :                mW2 + (size_t)l * 16384;
    }
    short* dst = out + (size_t)mat * 16384;
    int tr = (t >> 1) * 64, tc = (t & 1) * 64;
    for (int i = threadIdx.x; i < 4096; i += 256) {
        int r = i >> 6, c = i & 63;
        tileS[r][c] = Wsrc[(size_t)(tr + r) * 128 + (tc + c)];
    }
    __syncthreads();
    for (int i = threadIdx.x; i < 4096; i += 256) {
        int kl = i & 63, nl = i >> 6;
        int n = tc + nl, k = tr + kl;
        int fo = (((n >> 4) * 4 + (k >> 5)) * 64 + (((k >> 3) & 3) * 16 + (n & 15))) * 8 + (k & 7);
        dst[fo] = f2bf(tileS[kl][nl]);
    }
}

// ---------------- prep: layer-1 W1 [28,128] -> frag-ordered bf16, K padded to 32 ----------------
__global__ __launch_bounds__(256) void k_prep1(
    const float* __restrict__ W1, short* __restrict__ out)
{
    for (int i = threadIdx.x; i < 4096; i += 256) {
        int j = i & 7, sub = (i >> 3) & 63, nt = i >> 9;
        int quad = sub >> 4, l15 = sub & 15;
        int n = nt * 16 + l15, k = quad * 8 + j;
        out[i] = (k < 28) ? f2bf(W1[(size_t)k * 128 + n]) : (short)0;
    }
}

// ---------------- prep: layer-1 edge W2 [28,28] -> bf16 W^T padded [32][32] ----------------
__global__ __launch_bounds__(256) void k_prep28(
    const float* __restrict__ W2, short* __restrict__ out)
{
    for (int i = threadIdx.x; i < 32 * 32; i += 256) {
        int n = i >> 5, k = i & 31;
        out[i] = (n < 28 && k < 28) ? f2bf(W2[(size_t)k * 28 + n]) : (short)0;
    }
}

// ---------------- prep: x [N,28] f32 -> x_bf [N,32] bf16 ----------------
__global__ __launch_bounds__(256) void k_prepx(
    const float* __restrict__ x, unsigned short* __restrict__ xbf, int N)
{
    int total = N * 32;
    for (int i = blockIdx.x * 256 + threadIdx.x; i < total; i += gridDim.x * 256) {
        int n = i >> 5, c = i & 31;
        xbf[i] = (c < 28) ? f2bfu(x[(size_t)n * 28 + c]) : (unsigned short)0;
    }
}

// ---------------- CSR build ----------------
__global__ __launch_bounds__(256) void k_count(
    const int* __restrict__ ei, int* __restrict__ counts, int E)
{
    for (int e = blockIdx.x * 256 + threadIdx.x; e < E; e += gridDim.x * 256)
        atomicAdd(&counts[ei[E + e]], 1);
}

__global__ __launch_bounds__(256) void k_count2(
    const int* __restrict__ s2n, const float* __restrict__ mask,
    int* __restrict__ counts2, int N)
{
    for (int n = blockIdx.x * 256 + threadIdx.x; n < N; n += gridDim.x * 256)
        if (mask[n] != 0.f) atomicAdd(&counts2[s2n[n]], 1);
}

__global__ __launch_bounds__(256) void k_scanA(
    const int* __restrict__ counts, int* __restrict__ bsum, int N, int seg)
{
    __shared__ int red[256];
    int b = blockIdx.x;
    int lo = b * seg, hi = min(lo + seg, N);
    int s = 0;
    for (int i = lo + threadIdx.x; i < hi; i += 256) s += counts[i];
    red[threadIdx.x] = s;
    __syncthreads();
    for (int d = 128; d > 0; d >>= 1) {
        if (threadIdx.x < d) red[threadIdx.x] += red[threadIdx.x + d];
        __syncthreads();
    }
    if (threadIdx.x == 0) bsum[b] = red[0];
}

__global__ __launch_bounds__(256) void k_scanB(
    int* __restrict__ bsum, int nb, int* __restrict__ offs, int N)
{
    __shared__ int sh[256];
    int v = (threadIdx.x < nb) ? bsum[threadIdx.x] : 0;
    sh[threadIdx.x] = v;
    __syncthreads();
    for (int d = 1; d < 256; d <<= 1) {
        int t = (threadIdx.x >= d) ? sh[threadIdx.x - d] : 0;
        __syncthreads();
        sh[threadIdx.x] += t;
        __syncthreads();
    }
    if (threadIdx.x < nb) bsum[threadIdx.x] = sh[threadIdx.x] - v;
    if (threadIdx.x == 0) offs[N] = sh[255];
}

__global__ __launch_bounds__(256) void k_scanC(
    const int* __restrict__ counts, const int* __restrict__ bsum,
    int* __restrict__ offs, int* __restrict__ cursor, int N, int seg)
{
    __shared__ int sh[256];
    int b = blockIdx.x;
    int lo = b * seg, hi = min(lo + seg, N);
    int base = bsum[b];
    for (int t0 = lo; t0 < hi; t0 += 256) {
        int i = t0 + threadIdx.x;
        int v = (i < hi) ? counts[i] : 0;
        sh[threadIdx.x] = v;
        __syncthreads();
        for (int d = 1; d < 256; d <<= 1) {
            int t = (threadIdx.x >= d) ? sh[threadIdx.x - d] : 0;
            __syncthreads();
            sh[threadIdx.x] += t;
            __syncthreads();
        }
        int excl = base + sh[threadIdx.x] - v;
        if (i < hi) { offs[i] = excl; cursor[i] = excl; }
        int tileTotal = sh[255];
        __syncthreads();
        base += tileTotal;
    }
}

__global__ __launch_bounds__(256) void k_scatter(
    const int* __restrict__ ei, const float* __restrict__ ew,
    const float4* __restrict__ ea4,
    int* __restrict__ cursor, int2* __restrict__ pmeta,
    float4* __restrict__ pea4, int E)
{
    for (int e = blockIdx.x * 256 + threadIdx.x; e < E; e += gridDim.x * 256) {
        int d = ei[E + e];
        int pos = atomicAdd(&cursor[d], 1);
        pmeta[pos] = make_int2(ei[e], __float_as_int(ew[e]));
        pea4[pos] = ea4[e];
    }
}

__global__ __launch_bounds__(256) void k_scatter2(
    const int* __restrict__ s2n, const float* __restrict__ mask,
    int* __restrict__ cursor2, int* __restrict__ perm2, int N)
{
    for (int n = blockIdx.x * 256 + threadIdx.x; n < N; n += gridDim.x * 256)
        if (mask[n] != 0.f) {
            int pos = atomicAdd(&cursor2[s2n[n]], 1);
            perm2[pos] = n;
        }
}

// ---------------- hidden edge GEMM: barrier-free wave-local ----------------
__global__ __launch_bounds__(256, 3) void k_emsg(
    const float4* __restrict__ pea4,
    const float* __restrict__ W1, const float* __restrict__ b1,
    const short* __restrict__ W2f, const float* __restrict__ b2,
    unsigned short* __restrict__ emsg, const int* __restrict__ offs,
    int n0, int n1)
{
    __shared__ short As[64 * LDA];     // 17408 B
    __shared__ short Bs[16384];        // 32768 B  (frag-ordered W2)
    int e0 = offs[n0], e1 = offs[n1];
    int tid = threadIdx.x;
    int w = tid >> 6, lane = tid & 63;
    int l15 = lane & 15, quad = lane >> 4;
    int rb = w * 16;
    for (int i = tid; i < 2048; i += 256)
        *(bf16x8*)&Bs[i * 8] = *(const bf16x8*)&W2f[i * 8];
    int c2 = lane * 2;
    float w1a[4], w1b[4];
    #pragma unroll
    for (int a = 0; a < 4; ++a) { w1a[a] = W1[a * 128 + c2]; w1b[a] = W1[a * 128 + c2 + 1]; }
    float b1a = b1[c2], b1b = b1[c2 + 1];
    float b2r[8];
    #pragma unroll
    for (int nt = 0; nt < 8; ++nt) b2r[nt] = b2[nt * 16 + l15];
    __syncthreads();   // Bs ready (only barrier)

    const float* peaf = (const float*)pea4;
    int numTiles = (e1 - e0 + 63) >> 6;
    for (int tile = blockIdx.x; tile < numTiles; tile += gridDim.x) {
        int base = e0 + tile * 64;
        int eidx = base + rb + (lane >> 2);
        float v = (eidx < e1) ? peaf[(size_t)(base + rb) * 4 + lane] : 0.f;
        #pragma unroll
        for (int e = 0; e < 16; ++e) {
            float a0v = __shfl(v, e * 4 + 0);
            float a1v = __shfl(v, e * 4 + 1);
            float a2v = __shfl(v, e * 4 + 2);
            float a3v = __shfl(v, e * 4 + 3);
            float t0 = fmaf(a0v, w1a[0], fmaf(a1v, w1a[1], fmaf(a2v, w1a[2], fmaf(a3v, w1a[3], b1a))));
            float t1 = fmaf(a0v, w1b[0], fmaf(a1v, w1b[1], fmaf(a2v, w1b[2], fmaf(a3v, w1b[3], b1b))));
            unsigned int pk = ((unsigned int)f2bfu(fmaxf(t1, 0.f)) << 16) | f2bfu(fmaxf(t0, 0.f));
            *(unsigned int*)&As[(rb + e) * LDA + c2] = pk;
        }
        f32x4 acc[8];
        #pragma unroll
        for (int nt = 0; nt < 8; ++nt) acc[nt] = (f32x4){0.f, 0.f, 0.f, 0.f};
        #pragma unroll
        for (int kt = 0; kt < 4; ++kt) {
            bf16x8 af = *(bf16x8*)&As[(rb + l15) * LDA + kt * 32 + quad * 8];
            #pragma unroll
            for (int nt = 0; nt < 8; ++nt) {
                bf16x8 bf = *(const bf16x8*)&Bs[((nt * 4 + kt) * 64 + lane) * 8];
                acc[nt] = __builtin_amdgcn_mfma_f32_16x16x32_bf16(af, bf, acc[nt], 0, 0, 0);
            }
        }
        #pragma unroll
        for (int nt = 0; nt < 8; ++nt) {
            #pragma unroll
            for (int r = 0; r < 4; ++r)
                As[(rb + quad * 4 + r) * LDA + nt * 16 + l15] = f2bf(acc[nt][r] + b2r[nt]);
        }
        #pragma unroll
        for (int it = 0; it < 4; ++it) {
            int arow = rb + it * 4 + quad;
            int gr = base + arow;
            if (gr < e1)
                *(bf16x8*)&emsg[(size_t)(gr - e0) * 128 + l15 * 8] = *(bf16x8*)&As[arow * LDA + l15 * 8];
        }
    }
}

// ---------------- layer-1 edge MLP via MFMA ----------------
__global__ __launch_bounds__(256) void k_emsg28_mm(
    const float4* __restrict__ pea4,
    const float* __restrict__ W1, const float* __restrict__ b1,
    const short* __restrict__ W2t28,
    const float* __restrict__ b2,
    unsigned short* __restrict__ emsg28, int E)
{
    __shared__ short Bs[32 * 40];
    __shared__ short As[64 * 40];
    __shared__ float eas[64][4];
    __shared__ float b2s[32];
    int tid = threadIdx.x;
    for (int i = tid; i < 32 * 32; i += 256) {
        int n = i >> 5, k = i & 31;
        Bs[n * 40 + k] = W2t28[i];
    }
    if (tid < 32) b2s[tid] = (tid < 28) ? b2[tid] : 0.f;
    int j = tid & 31, sub = tid >> 5;
    float w10 = 0.f, w11 = 0.f, w12 = 0.f, w13 = 0.f, b1j = 0.f;
    if (j < 28) { w10 = W1[j]; w11 = W1[28 + j]; w12 = W1[56 + j]; w13 = W1[84 + j]; b1j = b1[j]; }
    int w = tid >> 6, lane = tid & 63;
    int l15 = lane & 15, quad = lane >> 4;
    __syncthreads();

    int numTiles = (E + 63) >> 6;
    for (int tile = blockIdx.x; tile < numTiles; tile += gridDim.x) {
        int base = tile * 64;
        __syncthreads();
        if (tid < 64) {
            int k = base + tid;
            float4 a = (k < E) ? pea4[k] : make_float4(0.f, 0.f, 0.f, 0.f);
            eas[tid][0] = a.x; eas[tid][1] = a.y; eas[tid][2] = a.z; eas[tid][3] = a.w;
        }
        __syncthreads();
        #pragma unroll
        for (int q = 0; q < 8; ++q) {
            int e = q * 8 + sub;
            float t = fmaf(eas[e][0], w10, fmaf(eas[e][1], w11,
                      fmaf(eas[e][2], w12, fmaf(eas[e][3], w13, b1j))));
            As[e * 40 + j] = (j < 28) ? f2bf(fmaxf(t, 0.f)) : (short)0;
        }
        __syncthreads();
        f32x4 acc[2];
        acc[0] = (f32x4){0.f, 0.f, 0.f, 0.f};
        acc[1] = (f32x4){0.f, 0.f, 0.f, 0.f};
        bf16x8 af = *(bf16x8*)&As[(w * 16 + l15) * 40 + quad * 8];
        #pragma unroll
        for (int nt = 0; nt < 2; ++nt) {
            bf16x8 bf = *(bf16x8*)&Bs[(nt * 16 + l15) * 40 + quad * 8];
            acc[nt] = __builtin_amdgcn_mfma_f32_16x16x32_bf16(af, bf, acc[nt], 0, 0, 0);
        }
        __syncthreads();
        #pragma unroll
        for (int nt = 0; nt < 2; ++nt) {
            int col = nt * 16 + l15;
            float bb = b2s[col];
            #pragma unroll
            for (int r = 0; r < 4; ++r)
                As[(w * 16 + quad * 4 + r) * 40 + col] = f2bf(acc[nt][r] + bb);
        }
        __syncthreads();
        for (int i = tid; i < 64 * 28; i += 256) {
            int row = i / 28, col = i - row * 28;
            int gr = base + row;
            if (gr < E) emsg28[(size_t)gr * 28 + col] = As[row * 40 + col];
        }
    }
}

// ---------------- gather node-chunk [n0,n1): batch-of-4 zero-padded slots ----------------
__global__ __launch_bounds__(256) void k_gather(
    const unsigned short* __restrict__ h, const int* __restrict__ offs,
    const int2* __restrict__ pmeta, const unsigned short* __restrict__ emsg,
    unsigned short* __restrict__ a0,
    const float* __restrict__ epsp, int epsIdx,
    int n0, int n1)
{
    int grp = threadIdx.x >> 5, lane = threadIdx.x & 31;
    int n = n0 + blockIdx.x * 8 + grp;
    if (n >= n1) return;
    int e0 = offs[n0];
    int k0 = offs[n], k1 = offs[n + 1];
    float s = 1.0f + epsp[epsIdx];
    ushort4 hv0 = *(const ushort4*)&h[(size_t)n * 128 + lane * 4];
    float m0 = s * bf2f(hv0.x), m1 = s * bf2f(hv0.y);
    float m2 = s * bf2f(hv0.z), m3 = s * bf2f(hv0.w);
    int2 mtA, mtB, mtC, mtD;
    ushort4 evA, hvA, evB, hvB, evC, hvC, evD, hvD;
    const ushort4 z4 = {0, 0, 0, 0};
    #define GSLOT(mt, ev, hv, kk) \
        if ((kk) < k1) { \
            mt = pmeta[kk]; \
            ev = *(const ushort4*)&emsg[(size_t)((kk) - e0) * 128 + lane * 4]; \
            hv = *(const ushort4*)&h[(size_t)mt.x * 128 + lane * 4]; \
        } else { mt = make_int2(0, 0); ev = z4; hv = z4; }
    #define GCONS(mt, ev, hv) { \
            float wv = __int_as_float(mt.y); \
            m0 += fmaxf(bf2f(hv.x) + bf2f(ev.x), 0.f) * wv; \
            m1 += fmaxf(bf2f(hv.y) + bf2f(ev.y), 0.f) * wv; \
            m2 += fmaxf(bf2f(hv.z) + bf2f(ev.z), 0.f) * wv; \
            m3 += fmaxf(bf2f(hv.w) + bf2f(ev.w), 0.f) * wv; }
    GSLOT(mtA, evA, hvA, k0)
    GSLOT(mtB, evB, hvB, k0 + 1)
    GSLOT(mtC, evC, hvC, k0 + 2)
    GSLOT(mtD, evD, hvD, k0 + 3)
    int k = k0;
    while (true) {
        GCONS(mtA, evA, hvA)
        GCONS(mtB, evB, hvB)
        GCONS(mtC, evC, hvC)
        GCONS(mtD, evD, hvD)
        k += 4;
        if (k >= k1) break;
        GSLOT(mtA, evA, hvA, k)
        GSLOT(mtB, evB, hvB, k + 1)
        GSLOT(mtC, evC, hvC, k + 2)
        GSLOT(mtD, evD, hvD, k + 3)
    }
    #undef GSLOT
    #undef GCONS
    ushort4 o;
    o.x = f2bfu(m0); o.y = f2bfu(m1); o.z = f2bfu(m2); o.w = f2bfu(m3);
    *(ushort4*)&a0[(size_t)n * 128 + lane * 4] = o;
}

// ---------------- gather (d=28): batch-of-4 zero-padded slots ----------------
__global__ __launch_bounds__(256) void k_gather28(
    const float* __restrict__ x, const unsigned short* __restrict__ xbf,
    const int* __restrict__ offs,
    const int2* __restrict__ pmeta, const unsigned short* __restrict__ emsg28,
    const float* __restrict__ eps1, float* __restrict__ u28, int N)
{
    int grp = threadIdx.x >> 5, lane = threadIdx.x & 31;
    int n = blockIdx.x * 8 + grp;
    if (n >= N || lane >= 28) return;
    float s = 1.0f + eps1[0];
    int k0 = offs[n], k1 = offs[n + 1];
    float m = 0.f;
    int2 mtA, mtB, mtC, mtD;
    unsigned short eA, xA, eB, xB, eC, xC, eD, xD;
    #define GSLOT28(mt, ee, xx, kk) \
        if ((kk) < k1) { \
            mt = pmeta[kk]; \
            ee = emsg28[(size_t)(kk) * 28 + lane]; \
            xx = xbf[(size_t)mt.x * 32 + lane]; \
        } else { mt = make_int2(0, 0); ee = 0; xx = 0; }
    #define GCONS28(mt, ee, xx) \
        m += fmaxf(bf2f(xx) + bf2f(ee), 0.f) * __int_as_float(mt.y);
    GSLOT28(mtA, eA, xA, k0)
    GSLOT28(mtB, eB, xB, k0 + 1)
    GSLOT28(mtC, eC, xC, k0 + 2)
    GSLOT28(mtD, eD, xD, k0 + 3)
    int k = k0;
    while (true) {
        GCONS28(mtA, eA, xA)
        GCONS28(mtB, eB, xB)
        GCONS28(mtC, eC, xC)
        GCONS28(mtD, eD, xD)
        k += 4;
        if (k >= k1) break;
        GSLOT28(mtA, eA, xA, k)
        GSLOT28(mtB, eB, xB, k + 1)
        GSLOT28(mtC, eC, xC, k + 2)
        GSLOT28(mtD, eD, xD, k + 3)
    }
    #undef GSLOT28
    #undef GCONS28
    u28[(size_t)n * 28 + lane] = fmaf(s, x[(size_t)n * 28 + lane], m);
}

// ---------------- plain node MLP (last layer): 8 waves x 32 rows ----------------
__global__ __launch_bounds__(512, 2) void k_mlp(
    const unsigned short* __restrict__ src, const short* __restrict__ W1f,
    const float* __restrict__ b1, const short* __restrict__ W2f,
    const float* __restrict__ b2, unsigned short* __restrict__ dst,
    float* __restrict__ stats, int N)
{
    __shared__ short As[256 * LDA];    // 69632 B
    __shared__ short Bs1[16384];       // 32768 B
    __shared__ short Bs2[16384];       // 32768 B
    __shared__ float sstat[256];
    int tid = threadIdx.x;
    for (int i = tid; i < 2048; i += 512) {
        *(bf16x8*)&Bs1[i * 8] = *(const bf16x8*)&W1f[i * 8];
        *(bf16x8*)&Bs2[i * 8] = *(const bf16x8*)&W2f[i * 8];
    }
    if (tid < 256) sstat[tid] = 0.f;
    int w = tid >> 6, lane = tid & 63;
    int l15 = lane & 15, quad = lane >> 4;
    int rb = w * 32;
    float b1r[8], b2r[8], lsum[8], lsq[8];
    #pragma unroll
    for (int nt = 0; nt < 8; ++nt) {
        b1r[nt] = b1[nt * 16 + l15]; b2r[nt] = b2[nt * 16 + l15];
        lsum[nt] = 0.f; lsq[nt] = 0.f;
    }
    int numTiles = (N + 255) >> 8;
    bf16x8 st[8];
    {
        int tile = blockIdx.x;
        if (tile < numTiles) {
            int base = tile * 256;
            #pragma unroll
            for (int kk = 0; kk < 8; ++kk) {
                int i = tid + kk * 512;
                int rr = base + (i >> 4);
                st[kk] = (rr < N) ? *(const bf16x8*)&src[(size_t)rr * 128 + (i & 15) * 8]
                                  : (bf16x8){0, 0, 0, 0, 0, 0, 0, 0};
            }
        }
    }
    __syncthreads();

    for (int tile = blockIdx.x; tile < numTiles; tile += gridDim.x) {
        int base = tile * 256;
        #pragma unroll
        for (int kk = 0; kk < 8; ++kk) {
            int i = tid + kk * 512;
            *(bf16x8*)&As[(i >> 4) * LDA + (i & 15) * 8] = st[kk];
        }
        int tnext = tile + gridDim.x;
        if (tnext < numTiles) {
            int bn = tnext * 256;
            #pragma unroll
            for (int kk = 0; kk < 8; ++kk) {
                int i = tid + kk * 512;
                int rr = bn + (i >> 4);
                st[kk] = (rr < N) ? *(const bf16x8*)&src[(size_t)rr * 128 + (i & 15) * 8]
                                  : (bf16x8){0, 0, 0, 0, 0, 0, 0, 0};
            }
        }
        __syncthreads();   // As staged
        f32x4 acc[2][8];
        #pragma unroll
        for (int rg = 0; rg < 2; ++rg)
            #pragma unroll
            for (int nt = 0; nt < 8; ++nt) acc[rg][nt] = (f32x4){0.f, 0.f, 0.f, 0.f};
        #pragma unroll
        for (int kt = 0; kt < 4; ++kt) {
            bf16x8 af0 = *(bf16x8*)&As[(rb + l15) * LDA + kt * 32 + quad * 8];
            bf16x8 af1 = *(bf16x8*)&As[(rb + 16 + l15) * LDA + kt * 32 + quad * 8];
            #pragma unroll
            for (int nt = 0; nt < 8; ++nt) {
                bf16x8 bf = *(const bf16x8*)&Bs1[((nt * 4 + kt) * 64 + lane) * 8];
                acc[0][nt] = __builtin_amdgcn_mfma_f32_16x16x32_bf16(af0, bf, acc[0][nt], 0, 0, 0);
                acc[1][nt] = __builtin_amdgcn_mfma_f32_16x16x32_bf16(af1, bf, acc[1][nt], 0, 0, 0);
            }
        }
        #pragma unroll
        for (int rg = 0; rg < 2; ++rg)
            #pragma unroll
            for (int nt = 0; nt < 8; ++nt)
                #pragma unroll
                for (int r = 0; r < 4; ++r)
                    As[(rb + rg * 16 + quad * 4 + r) * LDA + nt * 16 + l15] =
                        f2bf(fmaxf(acc[rg][nt][r] + b1r[nt], 0.f));
        #pragma unroll
        for (int rg = 0; rg < 2; ++rg)
            #pragma unroll
            for (int nt = 0; nt < 8; ++nt) acc[rg][nt] = (f32x4){0.f, 0.f, 0.f, 0.f};
        #pragma unroll
        for (int kt = 0; kt < 4; ++kt) {
            bf16x8 af0 = *(bf16x8*)&As[(rb + l15) * LDA + kt * 32 + quad * 8];
            bf16x8 af1 = *(bf16x8*)&As[(rb + 16 + l15) * LDA + kt * 32 + quad * 8];
            #pragma unroll
            for (int nt = 0; nt < 8; ++nt) {
                bf16x8 bf = *(const bf16x8*)&Bs2[((nt * 4 + kt) * 64 + lane) * 8];
                acc[0][nt] = __builtin_amdgcn_mfma_f32_16x16x32_bf16(af0, bf, acc[0][nt], 0, 0, 0);
                acc[1][nt] = __builtin_amdgcn_mfma_f32_16x16x32_bf16(af1, bf, acc[1][nt], 0, 0, 0);
            }
        }
        #pragma unroll
        for (int rg = 0; rg < 2; ++rg)
            #pragma unroll
            for (int nt = 0; nt < 8; ++nt) {
                int row0 = base + rb + rg * 16 + quad * 4;
                #pragma unroll
                for (int r = 0; r < 4; ++r) {
                    float z = acc[rg][nt][r] + b2r[nt];
                    if (row0 + r < N) { lsum[nt] += z; lsq[nt] = fmaf(z, z, lsq[nt]); }
                    As[(rb + rg * 16 + quad * 4 + r) * LDA + nt * 16 + l15] = f2bf(z);
                }
            }
        #pragma unroll
        for (int it = 0; it < 8; ++it) {
            int arow = rb + it * 4 + quad;
            int rr = base + arow;
            if (rr < N)
                *(bf16x8*)&dst[(size_t)rr * 128 + l15 * 8] = *(bf16x8*)&As[arow * LDA + l15 * 8];
        }
        __syncthreads();   // all As reads done before next stage-write
    }
    #pragma unroll
    for (int nt = 0; nt < 8; ++nt) {
        atomicAdd(&sstat[nt * 16 + l15], lsum[nt]);
        atomicAdd(&sstat[128 + nt * 16 + l15], lsq[nt]);
    }
    __syncthreads();
    if (tid < 256) atomicAdd(&stats[tid], sstat[tid]);
}

// ---------------- FUSED node MLP + BN (+residual) via grid sync ----------------
// grid MUST be 256 blocks (1/CU, coop-resident). z kept in bf16 regs across
// the grid sync (zreg[4][32], static indexing). Pass2: BN+relu, h += y.
__global__ __launch_bounds__(512, 2) void k_mlpbn(
    const unsigned short* __restrict__ src, const short* __restrict__ W1f,
    const float* __restrict__ b1, const short* __restrict__ W2f,
    const float* __restrict__ b2, unsigned short* __restrict__ hbuf,
    float* __restrict__ stats, const float* __restrict__ g,
    const float* __restrict__ bb, float invN, int N)
{
    __shared__ short As[256 * LDA];    // 69632 B
    __shared__ short Bs1[16384];       // 32768 B
    __shared__ short Bs2[16384];       // 32768 B
    __shared__ float sstat[256];
    int tid = threadIdx.x;
    for (int i = tid; i < 2048; i += 512) {
        *(bf16x8*)&Bs1[i * 8] = *(const bf16x8*)&W1f[i * 8];
        *(bf16x8*)&Bs2[i * 8] = *(const bf16x8*)&W2f[i * 8];
    }
    if (tid < 256) sstat[tid] = 0.f;
    int w = tid >> 6, lane = tid & 63;
    int l15 = lane & 15, quad = lane >> 4;
    int rb = w * 32;
    float b1r[8], b2r[8], lsum[8], lsq[8];
    #pragma unroll
    for (int nt = 0; nt < 8; ++nt) {
        b1r[nt] = b1[nt * 16 + l15]; b2r[nt] = b2[nt * 16 + l15];
        lsum[nt] = 0.f; lsq[nt] = 0.f;
    }
    unsigned int zreg[4][32];
    int numTiles = (N + 255) >> 8;
    __syncthreads();

    #pragma unroll
    for (int ti = 0; ti < 4; ++ti) {
        int tile = (int)blockIdx.x + ti * 256;
        if (tile < numTiles) {
            int base = tile * 256;
            #pragma unroll
            for (int kk = 0; kk < 8; ++kk) {
                int i = tid + kk * 512;
                int rr = base + (i >> 4);
                bf16x8 v = (rr < N) ? *(const bf16x8*)&src[(size_t)rr * 128 + (i & 15) * 8]
                                    : (bf16x8){0, 0, 0, 0, 0, 0, 0, 0};
                *(bf16x8*)&As[(i >> 4) * LDA + (i & 15) * 8] = v;
            }
            __syncthreads();   // As staged
            f32x4 acc[2][8];
            #pragma unroll
            for (int rg = 0; rg < 2; ++rg)
                #pragma unroll
                for (int nt = 0; nt < 8; ++nt) acc[rg][nt] = (f32x4){0.f, 0.f, 0.f, 0.f};
            #pragma unroll
            for (int kt = 0; kt < 4; ++kt) {
                bf16x8 af0 = *(bf16x8*)&As[(rb + l15) * LDA + kt * 32 + quad * 8];
                bf16x8 af1 = *(bf16x8*)&As[(rb + 16 + l15) * LDA + kt * 32 + quad * 8];
                #pragma unroll
                for (int nt = 0; nt < 8; ++nt) {
                    bf16x8 bf = *(const bf16x8*)&Bs1[((nt * 4 + kt) * 64 + lane) * 8];
                    acc[0][nt] = __builtin_amdgcn_mfma_f32_16x16x32_bf16(af0, bf, acc[0][nt], 0, 0, 0);
                    acc[1][nt] = __builtin_amdgcn_mfma_f32_16x16x32_bf16(af1, bf, acc[1][nt], 0, 0, 0);
                }
            }
            #pragma unroll
            for (int rg = 0; rg < 2; ++rg)
                #pragma unroll
                for (int nt = 0; nt < 8; ++nt)
                    #pragma unroll
                    for (int r = 0; r < 4; ++r)
                        As[(rb + rg * 16 + quad * 4 + r) * LDA + nt * 16 + l15] =
                            f2bf(fmaxf(acc[rg][nt][r] + b1r[nt], 0.f));
            #pragma unroll
            for (int rg = 0; rg < 2; ++rg)
                #pragma unroll
                for (int nt = 0; nt < 8; ++nt) acc[rg][nt] = (f32x4){0.f, 0.f, 0.f, 0.f};
            #pragma unroll
            for (int kt = 0; kt < 4; ++kt) {
                bf16x8 af0 = *(bf16x8*)&As[(rb + l15) * LDA + kt * 32 + quad * 8];
                bf16x8 af1 = *(bf16x8*)&As[(rb + 16 + l15) * LDA + kt * 32 + quad * 8];
                #pragma unroll
                for (int nt = 0; nt < 8; ++nt) {
                    bf16x8 bf = *(const bf16x8*)&Bs2[((nt * 4 + kt) * 64 + lane) * 8];
                    acc[0][nt] = __builtin_amdgcn_mfma_f32_16x16x32_bf16(af0, bf, acc[0][nt], 0, 0, 0);
                    acc[1][nt] = __builtin_amdgcn_mfma_f32_16x16x32_bf16(af1, bf, acc[1][nt], 0, 0, 0);
                }
            }
            // z -> registers (bf16 packed) + stats
            #pragma unroll
            for (int rg = 0; rg < 2; ++rg)
                #pragma unroll
                for (int nt = 0; nt < 8; ++nt) {
                    int row0 = base + rb + rg * 16 + quad * 4;
                    float zv0 = acc[rg][nt][0] + b2r[nt];
                    float zv1 = acc[rg][nt][1] + b2r[nt];
                    float zv2 = acc[rg][nt][2] + b2r[nt];
                    float zv3 = acc[rg][nt][3] + b2r[nt];
                    if (row0 + 0 < N) { lsum[nt] += zv0; lsq[nt] = fmaf(zv0, zv0, lsq[nt]); }
                    if (row0 + 1 < N) { lsum[nt] += zv1; lsq[nt] = fmaf(zv1, zv1, lsq[nt]); }
                    if (row0 + 2 < N) { lsum[nt] += zv2; lsq[nt] = fmaf(zv2, zv2, lsq[nt]); }
                    if (row0 + 3 < N) { lsum[nt] += zv3; lsq[nt] = fmaf(zv3, zv3, lsq[nt]); }
                    zreg[ti][rg * 16 + nt * 2 + 0] = ((unsigned int)f2bfu(zv1) << 16) | f2bfu(zv0);
                    zreg[ti][rg * 16 + nt * 2 + 1] = ((unsigned int)f2bfu(zv3) << 16) | f2bfu(zv2);
                }
            __syncthreads();   // As t-reads done before next tile stage
        }
    }
    // stats reduce: block LDS -> global atomics
    #pragma unroll
    for (int nt = 0; nt < 8; ++nt) {
        atomicAdd(&sstat[nt * 16 + l15], lsum[nt]);
        atomicAdd(&sstat[128 + nt * 16 + l15], lsq[nt]);
    }
    __syncthreads();
    if (tid < 256) atomicAdd(&stats[tid], sstat[tid]);
    __threadfence();
    cg::this_grid().sync();
    // pass 2: scale/shift, BN+relu, residual add into hbuf
    if (tid < 128) {
        const volatile float* vs = stats;
        float mu  = vs[tid] * invN;
        float var = fmaf(vs[128 + tid], invN, -mu * mu);
        float sc  = rsqrtf(fmaxf(var, 0.f) + BNEPS) * g[tid];
        sstat[tid] = sc;
        sstat[128 + tid] = fmaf(-mu, sc, bb[tid]);
    }
    __syncthreads();
    float scl[8], sht[8];
    #pragma unroll
    for (int nt = 0; nt < 8; ++nt) {
        int col = nt * 16 + l15;
        scl[nt] = sstat[col]; sht[nt] = sstat[128 + col];
    }
    #pragma unroll
    for (int ti = 0; ti < 4; ++ti) {
        int tile = (int)blockIdx.x + ti * 256;
        if (tile < numTiles) {
            int base = tile * 256;
            #pragma unroll
            for (int rg = 0; rg < 2; ++rg)
                #pragma unroll
                for (int nt = 0; nt < 8; ++nt)
                    #pragma unroll
                    for (int p = 0; p < 2; ++p) {
                        unsigned int pk = zreg[ti][rg * 16 + nt * 2 + p];
                        float y0 = fmaxf(fmaf(bf2f((unsigned short)(pk & 0xffff)), scl[nt], sht[nt]), 0.f);
                        float y1 = fmaxf(fmaf(bf2f((unsigned short)(pk >> 16)), scl[nt], sht[nt]), 0.f);
                        int row = rb + rg * 16 + quad * 4 + p * 2;
                        As[row * LDA + nt * 16 + l15] = f2bf(y0);
                        As[(row + 1) * LDA + nt * 16 + l15] = f2bf(y1);
                    }
            // store own rows with residual (wave-local LDS ordering)
            #pragma unroll
            for (int it = 0; it < 8; ++it) {
                int arow = rb + it * 4 + quad;
                int rr = base + arow;
                if (rr < N) {
                    u16x8 yv = *(u16x8*)&As[arow * LDA + l15 * 8];
                    u16x8 hv = *(const u16x8*)&hbuf[(size_t)rr * 128 + l15 * 8];
                    u16x8 o;
                    #pragma unroll
                    for (int r = 0; r < 8; ++r)
                        o[r] = f2bfu(bf2f(yv[r]) + bf2f(hv[r]));
                    *(u16x8*)&hbuf[(size_t)rr * 128 + l15 * 8] = o;
                }
            }
        }
    }
}

// ---------------- FUSED layer-1 node MLP + BN (no residual) via grid sync ----------------
__global__ __launch_bounds__(512, 2) void k_mlpbn1(
    const float* __restrict__ u28, const short* __restrict__ W1f,
    const float* __restrict__ b1, const short* __restrict__ W2f,
    const float* __restrict__ b2, unsigned short* __restrict__ hbuf,
    float* __restrict__ stats, const float* __restrict__ g,
    const float* __restrict__ bb, float invN, int N)
{
    __shared__ short A28[256 * 40];    // 20480 B
    __shared__ short As[256 * LDA];    // 69632 B
    __shared__ short Bs1[4096];        // 8192 B
    __shared__ short Bs2[16384];       // 32768 B
    __shared__ float sstat[256];
    int tid = threadIdx.x;
    if (tid < 512)
        *(bf16x8*)&Bs1[tid * 8] = *(const bf16x8*)&W1f[tid * 8];
    for (int i = tid; i < 2048; i += 512)
        *(bf16x8*)&Bs2[i * 8] = *(const bf16x8*)&W2f[i * 8];
    for (int i = tid; i < 1024; i += 512) {
        int row = i >> 2, c = 28 + (i & 3);
        A28[row * 40 + c] = 0;
    }
    if (tid < 256) sstat[tid] = 0.f;
    int w = tid >> 6, lane = tid & 63;
    int l15 = lane & 15, quad = lane >> 4;
    int rb = w * 32;
    float b1r[8], b2r[8], lsum[8], lsq[8];
    #pragma unroll
    for (int nt = 0; nt < 8; ++nt) {
        b1r[nt] = b1[nt * 16 + l15]; b2r[nt] = b2[nt * 16 + l15];
        lsum[nt] = 0.f; lsq[nt] = 0.f;
    }
    unsigned int zreg[4][32];
    int numTiles = (N + 255) >> 8;
    __syncthreads();

    #pragma unroll
    for (int ti = 0; ti < 4; ++ti) {
        int tile = (int)blockIdx.x + ti * 256;
        if (tile < numTiles) {
            int base = tile * 256;
            for (int i = tid; i < 256 * 28; i += 512) {
                int row = i / 28, col = i - row * 28;
                int rr = base + row;
                A28[row * 40 + col] = (rr < N) ? f2bf(u28[(size_t)rr * 28 + col]) : (short)0;
            }
            __syncthreads();   // A28 staged
            f32x4 acc[2][8];
            #pragma unroll
            for (int rg = 0; rg < 2; ++rg)
                #pragma unroll
                for (int nt = 0; nt < 8; ++nt) acc[rg][nt] = (f32x4){0.f, 0.f, 0.f, 0.f};
            {
                bf16x8 af0 = *(bf16x8*)&A28[(rb + l15) * 40 + quad * 8];
                bf16x8 af1 = *(bf16x8*)&A28[(rb + 16 + l15) * 40 + quad * 8];
                #pragma unroll
                for (int nt = 0; nt < 8; ++nt) {
                    bf16x8 bf = *(const bf16x8*)&Bs1[(nt * 64 + lane) * 8];
                    acc[0][nt] = __builtin_amdgcn_mfma_f32_16x16x32_bf16(af0, bf, acc[0][nt], 0, 0, 0);
                    acc[1][nt] = __builtin_amdgcn_mfma_f32_16x16x32_bf16(af1, bf, acc[1][nt], 0, 0, 0);
                }
            }
            #pragma unroll
            for (int rg = 0; rg < 2; ++rg)
                #pragma unroll
                for (int nt = 0; nt < 8; ++nt)
                    #pragma unroll
                    for (int r = 0; r < 4; ++r)
                        As[(rb + rg * 16 + quad * 4 + r) * LDA + nt * 16 + l15] =
                            f2bf(fmaxf(acc[rg][nt][r] + b1r[nt], 0.f));
            #pragma unroll
            for (int rg = 0; rg < 2; ++rg)
                #pragma unroll
                for (int nt = 0; nt < 8; ++nt) acc[rg][nt] = (f32x4){0.f, 0.f, 0.f, 0.f};
            #pragma unroll
            for (int kt = 0; kt < 4; ++kt) {
                bf16x8 af0 = *(bf16x8*)&As[(rb + l15) * LDA + kt * 32 + quad * 8];
                bf16x8 af1 = *(bf16x8*)&As[(rb + 16 + l15) * LDA + kt * 32 + quad * 8];
                #pragma unroll
                for (int nt = 0; nt < 8; ++nt) {
                    bf16x8 bf = *(const bf16x8*)&Bs2[((nt * 4 + kt) * 64 + lane) * 8];
                    acc[0][nt] = __builtin_amdgcn_mfma_f32_16x16x32_bf16(af0, bf, acc[0][nt], 0, 0, 0);
                    acc[1][nt] = __builtin_amdgcn_mfma_f32_16x16x32_bf16(af1, bf, acc[1][nt], 0, 0, 0);
                }
            }
            #pragma unroll
            for (int rg = 0; rg < 2; ++rg)
                #pragma unroll
                for (int nt = 0; nt < 8; ++nt) {
                    int row0 = base + rb + rg * 16 + quad * 4;
                    float zv0 = acc[rg][nt][0] + b2r[nt];
                    float zv1 = acc[rg][nt][1] + b2r[nt];
                    float zv2 = acc[rg][nt][2] + b2r[nt];
                    float zv3 = acc[rg][nt][3] + b2r[nt];
                    if (row0 + 0 < N) { lsum[nt] += zv0; lsq[nt] = fmaf(zv0, zv0, lsq[nt]); }
                    if (row0 + 1 < N) { lsum[nt] += zv1; lsq[nt] = fmaf(zv1, zv1, lsq[nt]); }
                    if (row0 + 2 < N) { lsum[nt] += zv2; lsq[nt] = fmaf(zv2, zv2, lsq[nt]); }
                    if (row0 + 3 < N) { lsum[nt] += zv3; lsq[nt] = fmaf(zv3, zv3, lsq[nt]); }
                    zreg[ti][rg * 16 + nt * 2 + 0] = ((unsigned int)f2bfu(zv1) << 16) | f2bfu(zv0);
                    zreg[ti][rg * 16 + nt * 2 + 1] = ((unsigned int)f2bfu(zv3) << 16) | f2bfu(zv2);
                }
            __syncthreads();
        }
    }
    #pragma unroll
    for (int nt = 0; nt < 8; ++nt) {
        atomicAdd(&sstat[nt * 16 + l15], lsum[nt]);
        atomicAdd(&sstat[128 + nt * 16 + l15], lsq[nt]);
    }
    __syncthreads();
    if (tid < 256) atomicAdd(&stats[tid], sstat[tid]);
    __threadfence();
    cg::this_grid().sync();
    if (tid < 128) {
        const volatile float* vs = stats;
        float mu  = vs[tid] * invN;
        float var = fmaf(vs[128 + tid], invN, -mu * mu);
        float sc  = rsqrtf(fmaxf(var, 0.f) + BNEPS) * g[tid];
        sstat[tid] = sc;
        sstat[128 + tid] = fmaf(-mu, sc, bb[tid]);
    }
    __syncthreads();
    float scl[8], sht[8];
    #pragma unroll
    for (int nt = 0; nt < 8; ++nt) {
        int col = nt * 16 + l15;
        scl[nt] = sstat[col]; sht[nt] = sstat[128 + col];
    }
    #pragma unroll
    for (int ti = 0; ti < 4; ++ti) {
        int tile = (int)blockIdx.x + ti * 256;
        if (tile < numTiles) {
            int base = tile * 256;
            #pragma unroll
            for (int rg = 0; rg < 2; ++rg)
                #pragma unroll
                for (int nt = 0; nt < 8; ++nt)
                    #pragma unroll
                    for (int p = 0; p < 2; ++p) {
                        unsigned int pk = zreg[ti][rg * 16 + nt * 2 + p];
                        float y0 = fmaxf(fmaf(bf2f((unsigned short)(pk & 0xffff)), scl[nt], sht[nt]), 0.f);
                        float y1 = fmaxf(fmaf(bf2f((unsigned short)(pk >> 16)), scl[nt], sht[nt]), 0.f);
                        int row = rb + rg * 16 + quad * 4 + p * 2;
                        As[row * LDA + nt * 16 + l15] = f2bf(y0);
                        As[(row + 1) * LDA + nt * 16 + l15] = f2bf(y1);
                    }
            #pragma unroll
            for (int it = 0; it < 8; ++it) {
                int arow = rb + it * 4 + quad;
                int rr = base + arow;
                if (rr < N)
                    *(u16x8*)&hbuf[(size_t)rr * 128 + l15 * 8] = *(u16x8*)&As[arow * LDA + l15 * 8];
            }
        }
    }
}

// ---------------- pool with fused last-layer BN+residual, stats folded in ----------------
__global__ __launch_bounds__(256) void k_poolbn(
    const unsigned short* __restrict__ z, const unsigned short* __restrict__ hprev,
    const float* __restrict__ stats, const float* __restrict__ g,
    const float* __restrict__ bb, float invN,
    const int* __restrict__ offs2, const int* __restrict__ perm2,
    float* __restrict__ out, int S)
{
    __shared__ float ss[256];
    if (threadIdx.x < 128) {
        int j = threadIdx.x;
        float mu  = stats[j] * invN;
        float var = fmaf(stats[128 + j], invN, -mu * mu);
        float sc  = rsqrtf(fmaxf(var, 0.f) + BNEPS) * g[j];
        ss[j] = sc;
        ss[128 + j] = fmaf(-mu, sc, bb[j]);
    }
    __syncthreads();
    int w = threadIdx.x >> 6, lane = threadIdx.x & 63;
    int s = blockIdx.x * 4 + w;
    if (s >= S) return;
    int c0 = lane * 2;
    float scl0 = ss[c0], scl1 = ss[c0 + 1];
    float sht0 = ss[128 + c0], sht1 = ss[128 + c0 + 1];
    int k0 = offs2[s], k1 = offs2[s + 1];
    float a0 = 0.f, a1 = 0.f;
    for (int k = k0; k < k1; ++k) {
        int n = perm2[k];
        ushort2 zv = *(const ushort2*)&z[(size_t)n * 128 + c0];
        ushort2 hv = *(const ushort2*)&hprev[(size_t)n * 128 + c0];
        a0 += fmaxf(fmaf(bf2f(zv.x), scl0, sht0), 0.f) + bf2f(hv.x);
        a1 += fmaxf(fmaf(bf2f(zv.y), scl1, sht1), 0.f) + bf2f(hv.y);
    }
    *(float2*)&out[(size_t)s * 128 + c0] = make_float2(a0, a1);
}

extern "C" void kernel_launch(void* const* d_in, const int* in_sizes, int n_in,
                              void* d_out, int out_size, void* d_ws, size_t ws_size,
                              hipStream_t stream) {
    const float* x    = (const float*)d_in[0];
    const int*   ei   = (const int*)d_in[1];
    const float* ea   = (const float*)d_in[2];
    const float* ew   = (const float*)d_in[3];
    const float* mask = (const float*)d_in[4];
    const int*   s2n  = (const int*)d_in[5];
    const float* be1W1 = (const float*)d_in[6];
    const float* be1b1 = (const float*)d_in[7];
    const float* be1W2 = (const float*)d_in[8];
    const float* be1b2 = (const float*)d_in[9];
    const float* m1W1  = (const float*)d_in[10];
    const float* m1b1  = (const float*)d_in[11];
    const float* m1W2  = (const float*)d_in[12];
    const float* m1b2  = (const float*)d_in[13];
    const float* bn1g  = (const float*)d_in[14];
    const float* bn1b  = (const float*)d_in[15];
    const float* eps1  = (const float*)d_in[16];
    const float* beW1  = (const float*)d_in[17];
    const float* beb1  = (const float*)d_in[18];
    const float* beW2  = (const float*)d_in[19];
    const float* beb2  = (const float*)d_in[20];
    const float* mW1   = (const float*)d_in[21];
    const float* mb1   = (const float*)d_in[22];
    const float* mW2   = (const float*)d_in[23];
    const float* mb2   = (const float*)d_in[24];
    const float* bng   = (const float*)d_in[25];
    const float* bnb   = (const float*)d_in[26];
    const float* epsL  = (const float*)d_in[27];

    const int N = in_sizes[0] / 28;
    const int E = in_sizes[1] / 2;
    const int S = out_size / 128;
    const float invN = 1.0f / (float)N;
    const int NS = N / 2;
    const int EMC = E / 2 + 8192;

    auto al16 = [](size_t v) { return (v + 15) & ~(size_t)15; };
    char* ws = (char*)d_ws;
    size_t offH      = 0;
    size_t offA0     = al16(offH + (size_t)N * 256);
    size_t offEm     = al16(offA0 + (size_t)N * 256);
    size_t emBytes   = (size_t)EMC * 256;
    if ((size_t)E * 56 > emBytes) emBytes = (size_t)E * 56;
    size_t offStats  = al16(offEm + emBytes);
    size_t offSS     = al16(offStats + 4096);
    size_t offWts    = al16(offSS + 1024);
    size_t offCounts = al16(offWts + 10 * 16384 * 2 + 4096 * 2 + 1024 * 2);
    size_t offOffs   = al16(offCounts + (size_t)N * 4);
    size_t offCursor = al16(offOffs + (size_t)(N + 1) * 4);
    size_t offPmeta  = al16(offCursor + (size_t)N * 4);
    size_t offPea    = al16(offPmeta + (size_t)E * 8);
    size_t offBsum   = al16(offPea + (size_t)E * 16);
    size_t offCnt2   = al16(offBsum + SCAN_NB * 4);
    size_t offOffs2  = al16(offCnt2 + (size_t)S * 4);
    size_t offCur2   = al16(offOffs2 + (size_t)(S + 1) * 4);
    size_t offPerm2  = al16(offCur2 + (size_t)S * 4);
    size_t need      = offPerm2 + (size_t)N * 4;
    if (ws_size < need) return;

    unsigned short* h    = (unsigned short*)(ws + offH);
    unsigned short* a0   = (unsigned short*)(ws + offA0);
    unsigned short* emsg = (unsigned short*)(ws + offEm);
    float* u28    = (float*)(ws + offA0);
    unsigned short* xbf = (unsigned short*)(ws + offA0 + 26214400);
    float* stats  = (float*)(ws + offStats);
    short* wts    = (short*)(ws + offWts);
    short* w1p    = wts + 10 * 16384;
    short* w2p28  = w1p + 4096;
    int*   counts = (int*)(ws + offCounts);
    int*   offs   = (int*)(ws + offOffs);
    int*   cursor = (int*)(ws + offCursor);
    int2*  pmeta  = (int2*)(ws + offPmeta);
    float4* pea4  = (float4*)(ws + offPea);
    int*   bsum   = (int*)(ws + offBsum);
    int*   cnt2   = (int*)(ws + offCnt2);
    int*   offs2  = (int*)(ws + offOffs2);
    int*   cur2   = (int*)(ws + offCur2);
    int*   perm2  = (int*)(ws + offPerm2);
    const float4* ea4 = (const float4*)ea;

    hipMemsetAsync(stats, 0, 4 * 256 * sizeof(float), stream);
    hipMemsetAsync(counts, 0, (size_t)N * sizeof(int), stream);
    hipMemsetAsync(cnt2, 0, (size_t)S * sizeof(int), stream);

    k_prep<<<40, 256, 0, stream>>>(m1W2, beW2, mW1, mW2, wts);
    k_prep1<<<1, 256, 0, stream>>>(m1W1, w1p);
    k_prep28<<<1, 256, 0, stream>>>(be1W2, w2p28);
    k_prepx<<<512, 256, 0, stream>>>(x, xbf, N);

    // ---- edge CSR (dst-sorted; attrs pre-permuted) ----
    const int seg = (N + SCAN_NB - 1) / SCAN_NB;
    k_count<<<1024, 256, 0, stream>>>(ei, counts, E);
    k_scanA<<<SCAN_NB, 256, 0, stream>>>(counts, bsum, N, seg);
    k_scanB<<<1, 256, 0, stream>>>(bsum, SCAN_NB, offs, N);
    k_scanC<<<SCAN_NB, 256, 0, stream>>>(counts, bsum, offs, cursor, N, seg);
    k_scatter<<<1024, 256, 0, stream>>>(ei, ew, ea4, cursor, pmeta, pea4, E);

    // ---- segment CSR ----
    const int seg2 = (S + SCAN_NB - 1) / SCAN_NB;
    k_count2<<<512, 256, 0, stream>>>(s2n, mask, cnt2, N);
    k_scanA<<<SCAN_NB, 256, 0, stream>>>(cnt2, bsum, S, seg2);
    k_scanB<<<1, 256, 0, stream>>>(bsum, SCAN_NB, offs2, S);
    k_scanC<<<SCAN_NB, 256, 0, stream>>>(cnt2, bsum, offs2, cur2, S, seg2);
    k_scatter2<<<512, 256, 0, stream>>>(s2n, mask, cur2, perm2, N);

    auto wt_be = [&](int l) { return wts + (size_t)(1 + 3 * l + 0) * 16384; };
    auto wt_m1 = [&](int l) { return wts + (size_t)(1 + 3 * l + 1) * 16384; };
    auto wt_m2 = [&](int l) { return wts + (size_t)(1 + 3 * l + 2) * 16384; };

    // ---- layer 1 (28 -> 128): fused MLP+BN (coop) ----
    k_emsg28_mm<<<2048, 256, 0, stream>>>(pea4, be1W1, be1b1, w2p28, be1b2, emsg, E);
    k_gather28<<<(N + 7) / 8, 256, 0, stream>>>(x, xbf, offs, pmeta, emsg, eps1, u28, N);
    {
        const float* u28c = u28;
        const short* w1fc = w1p;
        const float* b1c = m1b1;
        const short* w2fc = wts;   // m1W2 frag-ordered
        const float* b2c = m1b2;
        unsigned short* hc = h;
        float* stc = stats;
        const float* gc = bn1g;
        const float* bbc = bn1b;
        float invNc = invN;
        int Nc = N;
        void* args[] = { (void*)&u28c, (void*)&w1fc, (void*)&b1c, (void*)&w2fc,
                         (void*)&b2c, (void*)&hc, (void*)&stc, (void*)&gc,
                         (void*)&bbc, (void*)&invNc, (void*)&Nc };
        hipLaunchCooperativeKernel((const void*)k_mlpbn1, dim3(256), dim3(512),
                                   args, 0, stream);
    }

    // ---- layers 2..4 ----
    for (int l = 0; l < 3; ++l) {
        for (int c = 0; c < 2; ++c) {
            int n0 = (c == 0) ? 0 : NS;
            int n1 = (c == 0) ? NS : N;
            k_emsg<<<2048, 256, 0, stream>>>(pea4,
                beW1 + (size_t)l * 512, beb1 + (size_t)l * 128,
                wt_be(l), beb2 + (size_t)l * 128, emsg, offs, n0, n1);
            k_gather<<<(n1 - n0 + 7) / 8, 256, 0, stream>>>(h, offs, pmeta, emsg, a0,
                epsL, l, n0, n1);
        }
        if (l < 2) {
            const unsigned short* srcc = a0;
            const short* w1fc = wt_m1(l);
            const float* b1c = mb1 + (size_t)l * 128;
            const short* w2fc = wt_m2(l);
            const float* b2c = mb2 + (size_t)l * 128;
            unsigned short* hc = h;
            float* stc = stats + 256 * (l + 1);
            const float* gc = bng + (size_t)l * 128;
            const float* bbc = bnb + (size_t)l * 128;
            float invNc = invN;
            int Nc = N;
            void* args[] = { (void*)&srcc, (void*)&w1fc, (void*)&b1c, (void*)&w2fc,
                             (void*)&b2c, (void*)&hc, (void*)&stc, (void*)&gc,
                             (void*)&bbc, (void*)&invNc, (void*)&Nc };
            hipLaunchCooperativeKernel((const void*)k_mlpbn, dim3(256), dim3(512),
                                       args, 0, stream);
        } else {
            k_mlp<<<256, 512, 0, stream>>>(a0, wt_m1(l), mb1 + (size_t)l * 128,
                                           wt_m2(l), mb2 + (size_t)l * 128, a0,
                                           stats + 256 * (l + 1), N);
        }
    }

    // ---- pool with fused layer-4 BN+residual ----
    k_poolbn<<<(S + 3) / 4, 256, 0, stream>>>(a0, h, stats + 256 * 3,
        bng + 256, bnb + 256, invN, offs2, perm2, (float*)d_out, S);
}

// Round 11
// 1027.298 us; speedup vs baseline: 1.2568x; 1.2568x over previous
//
#include <hip/hip_runtime.h>
#include <hip/hip_bf16.h>

// ZINC GINE inner, round 23.
// r22 post-mortem: coop MLP+BN fusion regressed (zreg pinned VGPR at 128 ->
// spills; 128us). Reverted to r21 (1002.6us best).
// r23 vs r21: gathers get 2-way edge parallelism - one 64-lane wave per node,
// two 32-lane halves process alternating edges (halves the serial dependent-
// latency chain: ceil(deg/2) rounds), batch-2 per half (4 edges in flight),
// partials combined via shfl_xor(32). Half 1 accumulates from 0; half 0
// writes. Same for k_gather28. Everything else identical to r21.

#define BNEPS 1e-5f
#define LDA 136   // 128 + 8 shorts pad
#define SCAN_NB 240

typedef __attribute__((ext_vector_type(8))) short bf16x8;
typedef __attribute__((ext_vector_type(8))) unsigned short u16x8;
typedef __attribute__((ext_vector_type(4))) float f32x4;

__device__ inline short f2bf(float f) {
    __hip_bfloat16 h = __float2bfloat16(f);
    return *reinterpret_cast<short*>(&h);
}
__device__ inline unsigned short f2bfu(float f) {
    __hip_bfloat16 h = __float2bfloat16(f);
    return *reinterpret_cast<unsigned short*>(&h);
}
__device__ inline float bf2f(unsigned short u) {
    union { unsigned int i; float f; } v; v.i = ((unsigned int)u) << 16; return v.f;
}

// Fragment-ordered index for a [128][128] W^T (n = out col, k = in dim):
// frag (nt,kt) = ((n>>4)*4 + (k>>5)); lane = ((k>>3)&3)*16 + (n&15); j = k&7.
// Consumer: frag(nt,kt) for lane L is 16B at W[((nt*4+kt)*64 + L)*8].

// ---------------- prep: 10 f32 [128,128] weights -> bf16 W^T frag-ordered ----------------
__global__ __launch_bounds__(256) void k_prep(
    const float* __restrict__ m1W2, const float* __restrict__ beW2,
    const float* __restrict__ mW1, const float* __restrict__ mW2,
    short* __restrict__ out)
{
    __shared__ float tileS[64][65];
    int b = blockIdx.x, mat = b >> 2, t = b & 3;
    const float* Wsrc;
    if (mat == 0) Wsrc = m1W2;
    else {
        int l = (mat - 1) / 3, which = (mat - 1) % 3;
        Wsrc = (which == 0) ? beW2 + (size_t)l * 16384
             : (which == 1) ? mW1 + (size_t)l * 16384
             :                mW2 + (size_t)l * 16384;
    }
    short* dst = out + (size_t)mat * 16384;
    int tr = (t >> 1) * 64, tc = (t & 1) * 64;   // tr: k-range, tc: n-range
    for (int i = threadIdx.x; i < 4096; i += 256) {
        int r = i >> 6, c = i & 63;
        tileS[r][c] = Wsrc[(size_t)(tr + r) * 128 + (tc + c)];
    }
    __syncthreads();
    for (int i = threadIdx.x; i < 4096; i += 256) {
        int kl = i & 63, nl = i >> 6;
        int n = tc + nl, k = tr + kl;
        int fo = (((n >> 4) * 4 + (k >> 5)) * 64 + (((k >> 3) & 3) * 16 + (n & 15))) * 8 + (k & 7);
        dst[fo] = f2bf(tileS[kl][nl]);
    }
}

// ---------------- prep: layer-1 W1 [28,128] -> frag-ordered bf16, K padded to 32 ----------------
__global__ __launch_bounds__(256) void k_prep1(
    const float* __restrict__ W1, short* __restrict__ out)
{
    for (int i = threadIdx.x; i < 4096; i += 256) {
        int j = i & 7, sub = (i >> 3) & 63, nt = i >> 9;
        int quad = sub >> 4, l15 = sub & 15;
        int n = nt * 16 + l15, k = quad * 8 + j;
        out[i] = (k < 28) ? f2bf(W1[(size_t)k * 128 + n]) : (short)0;
    }
}

// ---------------- prep: layer-1 edge W2 [28,28] -> bf16 W^T padded [32][32] ----------------
__global__ __launch_bounds__(256) void k_prep28(
    const float* __restrict__ W2, short* __restrict__ out)
{
    for (int i = threadIdx.x; i < 32 * 32; i += 256) {
        int n = i >> 5, k = i & 31;
        out[i] = (n < 28 && k < 28) ? f2bf(W2[(size_t)k * 28 + n]) : (short)0;
    }
}

// ---------------- prep: x [N,28] f32 -> x_bf [N,32] bf16 ----------------
__global__ __launch_bounds__(256) void k_prepx(
    const float* __restrict__ x, unsigned short* __restrict__ xbf, int N)
{
    int total = N * 32;
    for (int i = blockIdx.x * 256 + threadIdx.x; i < total; i += gridDim.x * 256) {
        int n = i >> 5, c = i & 31;
        xbf[i] = (c < 28) ? f2bfu(x[(size_t)n * 28 + c]) : (unsigned short)0;
    }
}

// ---------------- CSR build ----------------
__global__ __launch_bounds__(256) void k_count(
    const int* __restrict__ ei, int* __restrict__ counts, int E)
{
    for (int e = blockIdx.x * 256 + threadIdx.x; e < E; e += gridDim.x * 256)
        atomicAdd(&counts[ei[E + e]], 1);
}

__global__ __launch_bounds__(256) void k_count2(
    const int* __restrict__ s2n, const float* __restrict__ mask,
    int* __restrict__ counts2, int N)
{
    for (int n = blockIdx.x * 256 + threadIdx.x; n < N; n += gridDim.x * 256)
        if (mask[n] != 0.f) atomicAdd(&counts2[s2n[n]], 1);
}

__global__ __launch_bounds__(256) void k_scanA(
    const int* __restrict__ counts, int* __restrict__ bsum, int N, int seg)
{
    __shared__ int red[256];
    int b = blockIdx.x;
    int lo = b * seg, hi = min(lo + seg, N);
    int s = 0;
    for (int i = lo + threadIdx.x; i < hi; i += 256) s += counts[i];
    red[threadIdx.x] = s;
    __syncthreads();
    for (int d = 128; d > 0; d >>= 1) {
        if (threadIdx.x < d) red[threadIdx.x] += red[threadIdx.x + d];
        __syncthreads();
    }
    if (threadIdx.x == 0) bsum[b] = red[0];
}

__global__ __launch_bounds__(256) void k_scanB(
    int* __restrict__ bsum, int nb, int* __restrict__ offs, int N)
{
    __shared__ int sh[256];
    int v = (threadIdx.x < nb) ? bsum[threadIdx.x] : 0;
    sh[threadIdx.x] = v;
    __syncthreads();
    for (int d = 1; d < 256; d <<= 1) {
        int t = (threadIdx.x >= d) ? sh[threadIdx.x - d] : 0;
        __syncthreads();
        sh[threadIdx.x] += t;
        __syncthreads();
    }
    if (threadIdx.x < nb) bsum[threadIdx.x] = sh[threadIdx.x] - v;
    if (threadIdx.x == 0) offs[N] = sh[255];
}

__global__ __launch_bounds__(256) void k_scanC(
    const int* __restrict__ counts, const int* __restrict__ bsum,
    int* __restrict__ offs, int* __restrict__ cursor, int N, int seg)
{
    __shared__ int sh[256];
    int b = blockIdx.x;
    int lo = b * seg, hi = min(lo + seg, N);
    int base = bsum[b];
    for (int t0 = lo; t0 < hi; t0 += 256) {
        int i = t0 + threadIdx.x;
        int v = (i < hi) ? counts[i] : 0;
        sh[threadIdx.x] = v;
        __syncthreads();
        for (int d = 1; d < 256; d <<= 1) {
            int t = (threadIdx.x >= d) ? sh[threadIdx.x - d] : 0;
            __syncthreads();
            sh[threadIdx.x] += t;
            __syncthreads();
        }
        int excl = base + sh[threadIdx.x] - v;
        if (i < hi) { offs[i] = excl; cursor[i] = excl; }
        int tileTotal = sh[255];
        __syncthreads();
        base += tileTotal;
    }
}

__global__ __launch_bounds__(256) void k_scatter(
    const int* __restrict__ ei, const float* __restrict__ ew,
    const float4* __restrict__ ea4,
    int* __restrict__ cursor, int2* __restrict__ pmeta,
    float4* __restrict__ pea4, int E)
{
    for (int e = blockIdx.x * 256 + threadIdx.x; e < E; e += gridDim.x * 256) {
        int d = ei[E + e];
        int pos = atomicAdd(&cursor[d], 1);
        pmeta[pos] = make_int2(ei[e], __float_as_int(ew[e]));
        pea4[pos] = ea4[e];
    }
}

__global__ __launch_bounds__(256) void k_scatter2(
    const int* __restrict__ s2n, const float* __restrict__ mask,
    int* __restrict__ cursor2, int* __restrict__ perm2, int N)
{
    for (int n = blockIdx.x * 256 + threadIdx.x; n < N; n += gridDim.x * 256)
        if (mask[n] != 0.f) {
            int pos = atomicAdd(&cursor2[s2n[n]], 1);
            perm2[pos] = n;
        }
}

// ---------------- hidden edge GEMM: barrier-free wave-local ----------------
__global__ __launch_bounds__(256, 3) void k_emsg(
    const float4* __restrict__ pea4,
    const float* __restrict__ W1, const float* __restrict__ b1,
    const short* __restrict__ W2f, const float* __restrict__ b2,
    unsigned short* __restrict__ emsg, const int* __restrict__ offs,
    int n0, int n1)
{
    __shared__ short As[64 * LDA];     // 17408 B
    __shared__ short Bs[16384];        // 32768 B  (frag-ordered W2)
    int e0 = offs[n0], e1 = offs[n1];
    int tid = threadIdx.x;
    int w = tid >> 6, lane = tid & 63;
    int l15 = lane & 15, quad = lane >> 4;
    int rb = w * 16;
    for (int i = tid; i < 2048; i += 256)
        *(bf16x8*)&Bs[i * 8] = *(const bf16x8*)&W2f[i * 8];
    int c2 = lane * 2;
    float w1a[4], w1b[4];
    #pragma unroll
    for (int a = 0; a < 4; ++a) { w1a[a] = W1[a * 128 + c2]; w1b[a] = W1[a * 128 + c2 + 1]; }
    float b1a = b1[c2], b1b = b1[c2 + 1];
    float b2r[8];
    #pragma unroll
    for (int nt = 0; nt < 8; ++nt) b2r[nt] = b2[nt * 16 + l15];
    __syncthreads();   // Bs ready (only barrier)

    const float* peaf = (const float*)pea4;
    int numTiles = (e1 - e0 + 63) >> 6;
    for (int tile = blockIdx.x; tile < numTiles; tile += gridDim.x) {
        int base = e0 + tile * 64;
        int eidx = base + rb + (lane >> 2);
        float v = (eidx < e1) ? peaf[(size_t)(base + rb) * 4 + lane] : 0.f;
        #pragma unroll
        for (int e = 0; e < 16; ++e) {
            float a0v = __shfl(v, e * 4 + 0);
            float a1v = __shfl(v, e * 4 + 1);
            float a2v = __shfl(v, e * 4 + 2);
            float a3v = __shfl(v, e * 4 + 3);
            float t0 = fmaf(a0v, w1a[0], fmaf(a1v, w1a[1], fmaf(a2v, w1a[2], fmaf(a3v, w1a[3], b1a))));
            float t1 = fmaf(a0v, w1b[0], fmaf(a1v, w1b[1], fmaf(a2v, w1b[2], fmaf(a3v, w1b[3], b1b))));
            unsigned int pk = ((unsigned int)f2bfu(fmaxf(t1, 0.f)) << 16) | f2bfu(fmaxf(t0, 0.f));
            *(unsigned int*)&As[(rb + e) * LDA + c2] = pk;
        }
        f32x4 acc[8];
        #pragma unroll
        for (int nt = 0; nt < 8; ++nt) acc[nt] = (f32x4){0.f, 0.f, 0.f, 0.f};
        #pragma unroll
        for (int kt = 0; kt < 4; ++kt) {
            bf16x8 af = *(bf16x8*)&As[(rb + l15) * LDA + kt * 32 + quad * 8];
            #pragma unroll
            for (int nt = 0; nt < 8; ++nt) {
                bf16x8 bf = *(const bf16x8*)&Bs[((nt * 4 + kt) * 64 + lane) * 8];
                acc[nt] = __builtin_amdgcn_mfma_f32_16x16x32_bf16(af, bf, acc[nt], 0, 0, 0);
            }
        }
        #pragma unroll
        for (int nt = 0; nt < 8; ++nt) {
            #pragma unroll
            for (int r = 0; r < 4; ++r)
                As[(rb + quad * 4 + r) * LDA + nt * 16 + l15] = f2bf(acc[nt][r] + b2r[nt]);
        }
        #pragma unroll
        for (int it = 0; it < 4; ++it) {
            int arow = rb + it * 4 + quad;
            int gr = base + arow;
            if (gr < e1)
                *(bf16x8*)&emsg[(size_t)(gr - e0) * 128 + l15 * 8] = *(bf16x8*)&As[arow * LDA + l15 * 8];
        }
    }
}

// ---------------- layer-1 edge MLP via MFMA (r13-style) ----------------
__global__ __launch_bounds__(256) void k_emsg28_mm(
    const float4* __restrict__ pea4,
    const float* __restrict__ W1, const float* __restrict__ b1,
    const short* __restrict__ W2t28,
    const float* __restrict__ b2,
    unsigned short* __restrict__ emsg28, int E)
{
    __shared__ short Bs[32 * 40];
    __shared__ short As[64 * 40];
    __shared__ float eas[64][4];
    __shared__ float b2s[32];
    int tid = threadIdx.x;
    for (int i = tid; i < 32 * 32; i += 256) {
        int n = i >> 5, k = i & 31;
        Bs[n * 40 + k] = W2t28[i];
    }
    if (tid < 32) b2s[tid] = (tid < 28) ? b2[tid] : 0.f;
    int j = tid & 31, sub = tid >> 5;
    float w10 = 0.f, w11 = 0.f, w12 = 0.f, w13 = 0.f, b1j = 0.f;
    if (j < 28) { w10 = W1[j]; w11 = W1[28 + j]; w12 = W1[56 + j]; w13 = W1[84 + j]; b1j = b1[j]; }
    int w = tid >> 6, lane = tid & 63;
    int l15 = lane & 15, quad = lane >> 4;
    __syncthreads();

    int numTiles = (E + 63) >> 6;
    for (int tile = blockIdx.x; tile < numTiles; tile += gridDim.x) {
        int base = tile * 64;
        __syncthreads();
        if (tid < 64) {
            int k = base + tid;
            float4 a = (k < E) ? pea4[k] : make_float4(0.f, 0.f, 0.f, 0.f);
            eas[tid][0] = a.x; eas[tid][1] = a.y; eas[tid][2] = a.z; eas[tid][3] = a.w;
        }
        __syncthreads();
        #pragma unroll
        for (int q = 0; q < 8; ++q) {
            int e = q * 8 + sub;
            float t = fmaf(eas[e][0], w10, fmaf(eas[e][1], w11,
                      fmaf(eas[e][2], w12, fmaf(eas[e][3], w13, b1j))));
            As[e * 40 + j] = (j < 28) ? f2bf(fmaxf(t, 0.f)) : (short)0;
        }
        __syncthreads();
        f32x4 acc[2];
        acc[0] = (f32x4){0.f, 0.f, 0.f, 0.f};
        acc[1] = (f32x4){0.f, 0.f, 0.f, 0.f};
        bf16x8 af = *(bf16x8*)&As[(w * 16 + l15) * 40 + quad * 8];
        #pragma unroll
        for (int nt = 0; nt < 2; ++nt) {
            bf16x8 bf = *(bf16x8*)&Bs[(nt * 16 + l15) * 40 + quad * 8];
            acc[nt] = __builtin_amdgcn_mfma_f32_16x16x32_bf16(af, bf, acc[nt], 0, 0, 0);
        }
        __syncthreads();
        #pragma unroll
        for (int nt = 0; nt < 2; ++nt) {
            int col = nt * 16 + l15;
            float bb = b2s[col];
            #pragma unroll
            for (int r = 0; r < 4; ++r)
                As[(w * 16 + quad * 4 + r) * 40 + col] = f2bf(acc[nt][r] + bb);
        }
        __syncthreads();
        for (int i = tid; i < 64 * 28; i += 256) {
            int row = i / 28, col = i - row * 28;
            int gr = base + row;
            if (gr < E) emsg28[(size_t)gr * 28 + col] = As[row * 40 + col];
        }
    }
}

// ---------------- gather [n0,n1): wave/node, 2 half-waves on alternating edges ----------------
__global__ __launch_bounds__(256) void k_gather(
    const unsigned short* __restrict__ h, const int* __restrict__ offs,
    const int2* __restrict__ pmeta, const unsigned short* __restrict__ emsg,
    unsigned short* __restrict__ a0,
    const float* __restrict__ epsp, int epsIdx,
    int n0, int n1)
{
    int wv = threadIdx.x >> 6, lane = threadIdx.x & 63;
    int half = lane >> 5, sub = lane & 31;
    int n = n0 + blockIdx.x * 4 + wv;
    if (n >= n1) return;
    int e0 = offs[n0];
    int k0 = offs[n], k1 = offs[n + 1];
    float s = (half == 0) ? 1.0f + epsp[epsIdx] : 0.f;
    ushort4 hv0 = *(const ushort4*)&h[(size_t)n * 128 + sub * 4];
    float m0 = s * bf2f(hv0.x), m1 = s * bf2f(hv0.y);
    float m2 = s * bf2f(hv0.z), m3 = s * bf2f(hv0.w);
    int2 mtA, mtB;
    ushort4 evA, hvA, evB, hvB;
    const ushort4 z4 = {0, 0, 0, 0};
    #define GSLOT(mt, ev, hv, kk) \
        if ((kk) < k1) { \
            mt = pmeta[kk]; \
            ev = *(const ushort4*)&emsg[(size_t)((kk) - e0) * 128 + sub * 4]; \
            hv = *(const ushort4*)&h[(size_t)mt.x * 128 + sub * 4]; \
        } else { mt = make_int2(0, 0); ev = z4; hv = z4; }
    #define GCONS(mt, ev, hv) { \
            float wv2 = __int_as_float(mt.y); \
            m0 += fmaxf(bf2f(hv.x) + bf2f(ev.x), 0.f) * wv2; \
            m1 += fmaxf(bf2f(hv.y) + bf2f(ev.y), 0.f) * wv2; \
            m2 += fmaxf(bf2f(hv.z) + bf2f(ev.z), 0.f) * wv2; \
            m3 += fmaxf(bf2f(hv.w) + bf2f(ev.w), 0.f) * wv2; }
    int kb = k0;
    GSLOT(mtA, evA, hvA, kb + half)
    GSLOT(mtB, evB, hvB, kb + 2 + half)
    while (true) {
        GCONS(mtA, evA, hvA)
        GCONS(mtB, evB, hvB)
        kb += 4;
        if (kb >= k1) break;
        GSLOT(mtA, evA, hvA, kb + half)
        GSLOT(mtB, evB, hvB, kb + 2 + half)
    }
    #undef GSLOT
    #undef GCONS
    m0 += __shfl_xor(m0, 32);
    m1 += __shfl_xor(m1, 32);
    m2 += __shfl_xor(m2, 32);
    m3 += __shfl_xor(m3, 32);
    if (half == 0) {
        ushort4 o;
        o.x = f2bfu(m0); o.y = f2bfu(m1); o.z = f2bfu(m2); o.w = f2bfu(m3);
        *(ushort4*)&a0[(size_t)n * 128 + sub * 4] = o;
    }
}

// ---------------- gather (d=28): wave/node, 2 half-waves ----------------
__global__ __launch_bounds__(256) void k_gather28(
    const float* __restrict__ x, const unsigned short* __restrict__ xbf,
    const int* __restrict__ offs,
    const int2* __restrict__ pmeta, const unsigned short* __restrict__ emsg28,
    const float* __restrict__ eps1, float* __restrict__ u28, int N)
{
    int wv = threadIdx.x >> 6, lane = threadIdx.x & 63;
    int half = lane >> 5, sub = lane & 31;
    int n = blockIdx.x * 4 + wv;
    if (n >= N) return;
    bool act = (sub < 28);
    float s = 1.0f + eps1[0];
    int k0 = offs[n], k1 = offs[n + 1];
    float m = 0.f;
    int2 mtA, mtB;
    unsigned short eA, xA, eB, xB;
    #define GSLOT28(mt, ee, xx, kk) \
        if ((kk) < k1 && act) { \
            mt = pmeta[kk]; \
            ee = emsg28[(size_t)(kk) * 28 + sub]; \
            xx = xbf[(size_t)mt.x * 32 + sub]; \
        } else { mt = make_int2(0, 0); ee = 0; xx = 0; }
    #define GCONS28(mt, ee, xx) \
        m += fmaxf(bf2f(xx) + bf2f(ee), 0.f) * __int_as_float(mt.y);
    int kb = k0;
    GSLOT28(mtA, eA, xA, kb + half)
    GSLOT28(mtB, eB, xB, kb + 2 + half)
    while (true) {
        GCONS28(mtA, eA, xA)
        GCONS28(mtB, eB, xB)
        kb += 4;
        if (kb >= k1) break;
        GSLOT28(mtA, eA, xA, kb + half)
        GSLOT28(mtB, eB, xB, kb + 2 + half)
    }
    #undef GSLOT28
    #undef GCONS28
    m += __shfl_xor(m, 32);
    if (half == 0 && act)
        u28[(size_t)n * 28 + sub] = fmaf(s, x[(size_t)n * 28 + sub], m);
}

// ---------------- fused node MLP (hidden): 8 waves x 32 rows, 256-row tiles ----------------
__global__ __launch_bounds__(512, 2) void k_mlp(
    const unsigned short* __restrict__ src, const short* __restrict__ W1f,
    const float* __restrict__ b1, const short* __restrict__ W2f,
    const float* __restrict__ b2, unsigned short* __restrict__ dst,
    float* __restrict__ stats, int N)
{
    __shared__ short As[256 * LDA];    // 69632 B
    __shared__ short Bs1[16384];       // 32768 B
    __shared__ short Bs2[16384];       // 32768 B
    __shared__ float sstat[256];
    int tid = threadIdx.x;
    for (int i = tid; i < 2048; i += 512) {
        *(bf16x8*)&Bs1[i * 8] = *(const bf16x8*)&W1f[i * 8];
        *(bf16x8*)&Bs2[i * 8] = *(const bf16x8*)&W2f[i * 8];
    }
    if (tid < 256) sstat[tid] = 0.f;
    int w = tid >> 6, lane = tid & 63;
    int l15 = lane & 15, quad = lane >> 4;
    int rb = w * 32;
    float b1r[8], b2r[8], lsum[8], lsq[8];
    #pragma unroll
    for (int nt = 0; nt < 8; ++nt) {
        b1r[nt] = b1[nt * 16 + l15]; b2r[nt] = b2[nt * 16 + l15];
        lsum[nt] = 0.f; lsq[nt] = 0.f;
    }
    int numTiles = (N + 255) >> 8;
    bf16x8 st[8];
    {
        int tile = blockIdx.x;
        if (tile < numTiles) {
            int base = tile * 256;
            #pragma unroll
            for (int kk = 0; kk < 8; ++kk) {
                int i = tid + kk * 512;
                int rr = base + (i >> 4);
                st[kk] = (rr < N) ? *(const bf16x8*)&src[(size_t)rr * 128 + (i & 15) * 8]
                                  : (bf16x8){0, 0, 0, 0, 0, 0, 0, 0};
            }
        }
    }
    __syncthreads();

    for (int tile = blockIdx.x; tile < numTiles; tile += gridDim.x) {
        int base = tile * 256;
        #pragma unroll
        for (int kk = 0; kk < 8; ++kk) {
            int i = tid + kk * 512;
            *(bf16x8*)&As[(i >> 4) * LDA + (i & 15) * 8] = st[kk];
        }
        int tnext = tile + gridDim.x;
        if (tnext < numTiles) {
            int bn = tnext * 256;
            #pragma unroll
            for (int kk = 0; kk < 8; ++kk) {
                int i = tid + kk * 512;
                int rr = bn + (i >> 4);
                st[kk] = (rr < N) ? *(const bf16x8*)&src[(size_t)rr * 128 + (i & 15) * 8]
                                  : (bf16x8){0, 0, 0, 0, 0, 0, 0, 0};
            }
        }
        __syncthreads();   // As staged
        f32x4 acc[2][8];
        #pragma unroll
        for (int rg = 0; rg < 2; ++rg)
            #pragma unroll
            for (int nt = 0; nt < 8; ++nt) acc[rg][nt] = (f32x4){0.f, 0.f, 0.f, 0.f};
        #pragma unroll
        for (int kt = 0; kt < 4; ++kt) {
            bf16x8 af0 = *(bf16x8*)&As[(rb + l15) * LDA + kt * 32 + quad * 8];
            bf16x8 af1 = *(bf16x8*)&As[(rb + 16 + l15) * LDA + kt * 32 + quad * 8];
            #pragma unroll
            for (int nt = 0; nt < 8; ++nt) {
                bf16x8 bf = *(const bf16x8*)&Bs1[((nt * 4 + kt) * 64 + lane) * 8];
                acc[0][nt] = __builtin_amdgcn_mfma_f32_16x16x32_bf16(af0, bf, acc[0][nt], 0, 0, 0);
                acc[1][nt] = __builtin_amdgcn_mfma_f32_16x16x32_bf16(af1, bf, acc[1][nt], 0, 0, 0);
            }
        }
        #pragma unroll
        for (int rg = 0; rg < 2; ++rg)
            #pragma unroll
            for (int nt = 0; nt < 8; ++nt)
                #pragma unroll
                for (int r = 0; r < 4; ++r)
                    As[(rb + rg * 16 + quad * 4 + r) * LDA + nt * 16 + l15] =
                        f2bf(fmaxf(acc[rg][nt][r] + b1r[nt], 0.f));
        #pragma unroll
        for (int rg = 0; rg < 2; ++rg)
            #pragma unroll
            for (int nt = 0; nt < 8; ++nt) acc[rg][nt] = (f32x4){0.f, 0.f, 0.f, 0.f};
        #pragma unroll
        for (int kt = 0; kt < 4; ++kt) {
            bf16x8 af0 = *(bf16x8*)&As[(rb + l15) * LDA + kt * 32 + quad * 8];
            bf16x8 af1 = *(bf16x8*)&As[(rb + 16 + l15) * LDA + kt * 32 + quad * 8];
            #pragma unroll
            for (int nt = 0; nt < 8; ++nt) {
                bf16x8 bf = *(const bf16x8*)&Bs2[((nt * 4 + kt) * 64 + lane) * 8];
                acc[0][nt] = __builtin_amdgcn_mfma_f32_16x16x32_bf16(af0, bf, acc[0][nt], 0, 0, 0);
                acc[1][nt] = __builtin_amdgcn_mfma_f32_16x16x32_bf16(af1, bf, acc[1][nt], 0, 0, 0);
            }
        }
        #pragma unroll
        for (int rg = 0; rg < 2; ++rg)
            #pragma unroll
            for (int nt = 0; nt < 8; ++nt) {
                int row0 = base + rb + rg * 16 + quad * 4;
                #pragma unroll
                for (int r = 0; r < 4; ++r) {
                    float z = acc[rg][nt][r] + b2r[nt];
                    if (row0 + r < N) { lsum[nt] += z; lsq[nt] = fmaf(z, z, lsq[nt]); }
                    As[(rb + rg * 16 + quad * 4 + r) * LDA + nt * 16 + l15] = f2bf(z);
                }
            }
        #pragma unroll
        for (int it = 0; it < 8; ++it) {
            int arow = rb + it * 4 + quad;
            int rr = base + arow;
            if (rr < N)
                *(bf16x8*)&dst[(size_t)rr * 128 + l15 * 8] = *(bf16x8*)&As[arow * LDA + l15 * 8];
        }
        __syncthreads();   // all As reads done before next stage-write
    }
    #pragma unroll
    for (int nt = 0; nt < 8; ++nt) {
        atomicAdd(&sstat[nt * 16 + l15], lsum[nt]);
        atomicAdd(&sstat[128 + nt * 16 + l15], lsq[nt]);
    }
    __syncthreads();
    if (tid < 256) atomicAdd(&stats[tid], sstat[tid]);
}

// ---------------- fused layer-1 node MLP ----------------
__global__ __launch_bounds__(512, 2) void k_mlp1(
    const float* __restrict__ u28, const short* __restrict__ W1f,
    const float* __restrict__ b1, const short* __restrict__ W2f,
    const float* __restrict__ b2, unsigned short* __restrict__ dst,
    float* __restrict__ stats, int N)
{
    __shared__ short A28[256 * 40];    // 20480 B
    __shared__ short As[256 * LDA];    // 69632 B
    __shared__ short Bs1[4096];        // 8192 B (frag-ordered, K padded 32)
    __shared__ short Bs2[16384];       // 32768 B
    __shared__ float sstat[256];
    int tid = threadIdx.x;
    if (tid < 512) {
        int i = tid;
        *(bf16x8*)&Bs1[i * 8] = *(const bf16x8*)&W1f[i * 8];
    }
    for (int i = tid; i < 2048; i += 512)
        *(bf16x8*)&Bs2[i * 8] = *(const bf16x8*)&W2f[i * 8];
    for (int i = tid; i < 1024; i += 512) {
        int row = i >> 2, c = 28 + (i & 3);
        A28[row * 40 + c] = 0;
    }
    if (tid < 256) sstat[tid] = 0.f;
    int w = tid >> 6, lane = tid & 63;
    int l15 = lane & 15, quad = lane >> 4;
    int rb = w * 32;
    float b1r[8], b2r[8], lsum[8], lsq[8];
    #pragma unroll
    for (int nt = 0; nt < 8; ++nt) {
        b1r[nt] = b1[nt * 16 + l15]; b2r[nt] = b2[nt * 16 + l15];
        lsum[nt] = 0.f; lsq[nt] = 0.f;
    }
    int numTiles = (N + 255) >> 8;
    float stf[14];
    {
        int tile = blockIdx.x;
        if (tile < numTiles) {
            int base = tile * 256;
            #pragma unroll
            for (int kk = 0; kk < 14; ++kk) {
                int idx = tid + kk * 512;
                int row = idx / 28, col = idx - row * 28;
                int rr = base + row;
                stf[kk] = (rr < N) ? u28[(size_t)rr * 28 + col] : 0.f;
            }
        }
    }
    __syncthreads();

    for (int tile = blockIdx.x; tile < numTiles; tile += gridDim.x) {
        int base = tile * 256;
        #pragma unroll
        for (int kk = 0; kk < 14; ++kk) {
            int idx = tid + kk * 512;
            int row = idx / 28, col = idx - row * 28;
            A28[row * 40 + col] = f2bf(stf[kk]);
        }
        int tnext = tile + gridDim.x;
        if (tnext < numTiles) {
            int bn = tnext * 256;
            #pragma unroll
            for (int kk = 0; kk < 14; ++kk) {
                int idx = tid + kk * 512;
                int row = idx / 28, col = idx - row * 28;
                int rr = bn + row;
                stf[kk] = (rr < N) ? u28[(size_t)rr * 28 + col] : 0.f;
            }
        }
        __syncthreads();   // A28 staged
        f32x4 acc[2][8];
        #pragma unroll
        for (int rg = 0; rg < 2; ++rg)
            #pragma unroll
            for (int nt = 0; nt < 8; ++nt) acc[rg][nt] = (f32x4){0.f, 0.f, 0.f, 0.f};
        {
            bf16x8 af0 = *(bf16x8*)&A28[(rb + l15) * 40 + quad * 8];
            bf16x8 af1 = *(bf16x8*)&A28[(rb + 16 + l15) * 40 + quad * 8];
            #pragma unroll
            for (int nt = 0; nt < 8; ++nt) {
                bf16x8 bf = *(const bf16x8*)&Bs1[(nt * 64 + lane) * 8];
                acc[0][nt] = __builtin_amdgcn_mfma_f32_16x16x32_bf16(af0, bf, acc[0][nt], 0, 0, 0);
                acc[1][nt] = __builtin_amdgcn_mfma_f32_16x16x32_bf16(af1, bf, acc[1][nt], 0, 0, 0);
            }
        }
        #pragma unroll
        for (int rg = 0; rg < 2; ++rg)
            #pragma unroll
            for (int nt = 0; nt < 8; ++nt)
                #pragma unroll
                for (int r = 0; r < 4; ++r)
                    As[(rb + rg * 16 + quad * 4 + r) * LDA + nt * 16 + l15] =
                        f2bf(fmaxf(acc[rg][nt][r] + b1r[nt], 0.f));
        __syncthreads();
        #pragma unroll
        for (int rg = 0; rg < 2; ++rg)
            #pragma unroll
            for (int nt = 0; nt < 8; ++nt) acc[rg][nt] = (f32x4){0.f, 0.f, 0.f, 0.f};
        #pragma unroll
        for (int kt = 0; kt < 4; ++kt) {
            bf16x8 af0 = *(bf16x8*)&As[(rb + l15) * LDA + kt * 32 + quad * 8];
            bf16x8 af1 = *(bf16x8*)&As[(rb + 16 + l15) * LDA + kt * 32 + quad * 8];
            #pragma unroll
            for (int nt = 0; nt < 8; ++nt) {
                bf16x8 bf = *(const bf16x8*)&Bs2[((nt * 4 + kt) * 64 + lane) * 8];
                acc[0][nt] = __builtin_amdgcn_mfma_f32_16x16x32_bf16(af0, bf, acc[0][nt], 0, 0, 0);
                acc[1][nt] = __builtin_amdgcn_mfma_f32_16x16x32_bf16(af1, bf, acc[1][nt], 0, 0, 0);
            }
        }
        #pragma unroll
        for (int rg = 0; rg < 2; ++rg)
            #pragma unroll
            for (int nt = 0; nt < 8; ++nt) {
                int row0 = base + rb + rg * 16 + quad * 4;
                #pragma unroll
                for (int r = 0; r < 4; ++r) {
                    float z = acc[rg][nt][r] + b2r[nt];
                    if (row0 + r < N) { lsum[nt] += z; lsq[nt] = fmaf(z, z, lsq[nt]); }
                    As[(rb + rg * 16 + quad * 4 + r) * LDA + nt * 16 + l15] = f2bf(z);
                }
            }
        #pragma unroll
        for (int it = 0; it < 8; ++it) {
            int arow = rb + it * 4 + quad;
            int rr = base + arow;
            if (rr < N)
                *(bf16x8*)&dst[(size_t)rr * 128 + l15 * 8] = *(bf16x8*)&As[arow * LDA + l15 * 8];
        }
        __syncthreads();
    }
    #pragma unroll
    for (int nt = 0; nt < 8; ++nt) {
        atomicAdd(&sstat[nt * 16 + l15], lsum[nt]);
        atomicAdd(&sstat[128 + nt * 16 + l15], lsq[nt]);
    }
    __syncthreads();
    if (tid < 256) atomicAdd(&stats[tid], sstat[tid]);
}

// ---------------- BN-apply+relu(+residual), stats folded in ----------------
__global__ __launch_bounds__(256) void k_bn(
    const unsigned short* __restrict__ z, const float* __restrict__ stats,
    const float* __restrict__ g, const float* __restrict__ bb, float invN,
    unsigned short* __restrict__ h, int residual, int N)
{
    __shared__ float ss[256];
    if (threadIdx.x < 128) {
        int j = threadIdx.x;
        float mu  = stats[j] * invN;
        float var = fmaf(stats[128 + j], invN, -mu * mu);
        float sc  = rsqrtf(fmaxf(var, 0.f) + BNEPS) * g[j];
        ss[j] = sc;
        ss[128 + j] = fmaf(-mu, sc, bb[j]);
    }
    __syncthreads();
    int idx8 = blockIdx.x * 256 + threadIdx.x;
    int stride = gridDim.x * 256;
    int c0 = (idx8 & 15) * 8;
    float scl[8], sht[8];
    #pragma unroll
    for (int r = 0; r < 8; ++r) { scl[r] = ss[c0 + r]; sht[r] = ss[128 + c0 + r]; }
    int total8 = N * 16;
    for (; idx8 < total8; idx8 += stride) {
        int n = idx8 >> 4;
        u16x8 z8 = *(const u16x8*)&z[(size_t)n * 128 + c0];
        float hn[8];
        #pragma unroll
        for (int r = 0; r < 8; ++r)
            hn[r] = fmaxf(fmaf(bf2f(z8[r]), scl[r], sht[r]), 0.f);
        if (residual) {
            u16x8 h8 = *(const u16x8*)&h[(size_t)n * 128 + c0];
            #pragma unroll
            for (int r = 0; r < 8; ++r) hn[r] += bf2f(h8[r]);
        }
        u16x8 o;
        #pragma unroll
        for (int r = 0; r < 8; ++r) o[r] = f2bfu(hn[r]);
        *(u16x8*)&h[(size_t)n * 128 + c0] = o;
    }
}

// ---------------- pool with fused last-layer BN+residual, stats folded in ----------------
__global__ __launch_bounds__(256) void k_poolbn(
    const unsigned short* __restrict__ z, const unsigned short* __restrict__ hprev,
    const float* __restrict__ stats, const float* __restrict__ g,
    const float* __restrict__ bb, float invN,
    const int* __restrict__ offs2, const int* __restrict__ perm2,
    float* __restrict__ out, int S)
{
    __shared__ float ss[256];
    if (threadIdx.x < 128) {
        int j = threadIdx.x;
        float mu  = stats[j] * invN;
        float var = fmaf(stats[128 + j], invN, -mu * mu);
        float sc  = rsqrtf(fmaxf(var, 0.f) + BNEPS) * g[j];
        ss[j] = sc;
        ss[128 + j] = fmaf(-mu, sc, bb[j]);
    }
    __syncthreads();
    int w = threadIdx.x >> 6, lane = threadIdx.x & 63;
    int s = blockIdx.x * 4 + w;
    if (s >= S) return;
    int c0 = lane * 2;
    float scl0 = ss[c0], scl1 = ss[c0 + 1];
    float sht0 = ss[128 + c0], sht1 = ss[128 + c0 + 1];
    int k0 = offs2[s], k1 = offs2[s + 1];
    float a0 = 0.f, a1 = 0.f;
    for (int k = k0; k < k1; ++k) {
        int n = perm2[k];
        ushort2 zv = *(const ushort2*)&z[(size_t)n * 128 + c0];
        ushort2 hv = *(const ushort2*)&hprev[(size_t)n * 128 + c0];
        a0 += fmaxf(fmaf(bf2f(zv.x), scl0, sht0), 0.f) + bf2f(hv.x);
        a1 += fmaxf(fmaf(bf2f(zv.y), scl1, sht1), 0.f) + bf2f(hv.y);
    }
    *(float2*)&out[(size_t)s * 128 + c0] = make_float2(a0, a1);
}

extern "C" void kernel_launch(void* const* d_in, const int* in_sizes, int n_in,
                              void* d_out, int out_size, void* d_ws, size_t ws_size,
                              hipStream_t stream) {
    const float* x    = (const float*)d_in[0];
    const int*   ei   = (const int*)d_in[1];
    const float* ea   = (const float*)d_in[2];
    const float* ew   = (const float*)d_in[3];
    const float* mask = (const float*)d_in[4];
    const int*   s2n  = (const int*)d_in[5];
    const float* be1W1 = (const float*)d_in[6];
    const float* be1b1 = (const float*)d_in[7];
    const float* be1W2 = (const float*)d_in[8];
    const float* be1b2 = (const float*)d_in[9];
    const float* m1W1  = (const float*)d_in[10];
    const float* m1b1  = (const float*)d_in[11];
    const float* m1W2  = (const float*)d_in[12];
    const float* m1b2  = (const float*)d_in[13];
    const float* bn1g  = (const float*)d_in[14];
    const float* bn1b  = (const float*)d_in[15];
    const float* eps1  = (const float*)d_in[16];
    const float* beW1  = (const float*)d_in[17];
    const float* beb1  = (const float*)d_in[18];
    const float* beW2  = (const float*)d_in[19];
    const float* beb2  = (const float*)d_in[20];
    const float* mW1   = (const float*)d_in[21];
    const float* mb1   = (const float*)d_in[22];
    const float* mW2   = (const float*)d_in[23];
    const float* mb2   = (const float*)d_in[24];
    const float* bng   = (const float*)d_in[25];
    const float* bnb   = (const float*)d_in[26];
    const float* epsL  = (const float*)d_in[27];

    const int N = in_sizes[0] / 28;
    const int E = in_sizes[1] / 2;
    const int S = out_size / 128;
    const float invN = 1.0f / (float)N;
    const int NS = N / 2;
    const int EMC = E / 2 + 8192;

    auto al16 = [](size_t v) { return (v + 15) & ~(size_t)15; };
    char* ws = (char*)d_ws;
    size_t offH      = 0;
    size_t offA0     = al16(offH + (size_t)N * 256);
    size_t offEm     = al16(offA0 + (size_t)N * 256);
    size_t emBytes   = (size_t)EMC * 256;
    if ((size_t)E * 56 > emBytes) emBytes = (size_t)E * 56;
    size_t offStats  = al16(offEm + emBytes);
    size_t offSS     = al16(offStats + 4096);
    size_t offWts    = al16(offSS + 1024);
    size_t offCounts = al16(offWts + 10 * 16384 * 2 + 4096 * 2 + 1024 * 2);
    size_t offOffs   = al16(offCounts + (size_t)N * 4);
    size_t offCursor = al16(offOffs + (size_t)(N + 1) * 4);
    size_t offPmeta  = al16(offCursor + (size_t)N * 4);
    size_t offPea    = al16(offPmeta + (size_t)E * 8);
    size_t offBsum   = al16(offPea + (size_t)E * 16);
    size_t offCnt2   = al16(offBsum + SCAN_NB * 4);
    size_t offOffs2  = al16(offCnt2 + (size_t)S * 4);
    size_t offCur2   = al16(offOffs2 + (size_t)(S + 1) * 4);
    size_t offPerm2  = al16(offCur2 + (size_t)S * 4);
    size_t need      = offPerm2 + (size_t)N * 4;
    if (ws_size < need) return;

    unsigned short* h    = (unsigned short*)(ws + offH);
    unsigned short* a0   = (unsigned short*)(ws + offA0);
    unsigned short* emsg = (unsigned short*)(ws + offEm);
    float* u28    = (float*)(ws + offA0);
    unsigned short* xbf = (unsigned short*)(ws + offA0 + 26214400);
    float* stats  = (float*)(ws + offStats);
    short* wts    = (short*)(ws + offWts);
    short* w1p    = wts + 10 * 16384;
    short* w2p28  = w1p + 4096;
    int*   counts = (int*)(ws + offCounts);
    int*   offs   = (int*)(ws + offOffs);
    int*   cursor = (int*)(ws + offCursor);
    int2*  pmeta  = (int2*)(ws + offPmeta);
    float4* pea4  = (float4*)(ws + offPea);
    int*   bsum   = (int*)(ws + offBsum);
    int*   cnt2   = (int*)(ws + offCnt2);
    int*   offs2  = (int*)(ws + offOffs2);
    int*   cur2   = (int*)(ws + offCur2);
    int*   perm2  = (int*)(ws + offPerm2);
    const float4* ea4 = (const float4*)ea;

    hipMemsetAsync(stats, 0, 4 * 256 * sizeof(float), stream);
    hipMemsetAsync(counts, 0, (size_t)N * sizeof(int), stream);
    hipMemsetAsync(cnt2, 0, (size_t)S * sizeof(int), stream);

    k_prep<<<40, 256, 0, stream>>>(m1W2, beW2, mW1, mW2, wts);
    k_prep1<<<1, 256, 0, stream>>>(m1W1, w1p);
    k_prep28<<<1, 256, 0, stream>>>(be1W2, w2p28);
    k_prepx<<<512, 256, 0, stream>>>(x, xbf, N);

    // ---- edge CSR (dst-sorted; attrs pre-permuted) ----
    const int seg = (N + SCAN_NB - 1) / SCAN_NB;
    k_count<<<1024, 256, 0, stream>>>(ei, counts, E);
    k_scanA<<<SCAN_NB, 256, 0, stream>>>(counts, bsum, N, seg);
    k_scanB<<<1, 256, 0, stream>>>(bsum, SCAN_NB, offs, N);
    k_scanC<<<SCAN_NB, 256, 0, stream>>>(counts, bsum, offs, cursor, N, seg);
    k_scatter<<<1024, 256, 0, stream>>>(ei, ew, ea4, cursor, pmeta, pea4, E);

    // ---- segment CSR ----
    const int seg2 = (S + SCAN_NB - 1) / SCAN_NB;
    k_count2<<<512, 256, 0, stream>>>(s2n, mask, cnt2, N);
    k_scanA<<<SCAN_NB, 256, 0, stream>>>(cnt2, bsum, S, seg2);
    k_scanB<<<1, 256, 0, stream>>>(bsum, SCAN_NB, offs2, S);
    k_scanC<<<SCAN_NB, 256, 0, stream>>>(cnt2, bsum, offs2, cur2, S, seg2);
    k_scatter2<<<512, 256, 0, stream>>>(s2n, mask, cur2, perm2, N);

    auto wt_be = [&](int l) { return wts + (size_t)(1 + 3 * l + 0) * 16384; };
    auto wt_m1 = [&](int l) { return wts + (size_t)(1 + 3 * l + 1) * 16384; };
    auto wt_m2 = [&](int l) { return wts + (size_t)(1 + 3 * l + 2) * 16384; };

    // ---- layer 1 (28 -> 128) ----
    k_emsg28_mm<<<2048, 256, 0, stream>>>(pea4, be1W1, be1b1, w2p28, be1b2, emsg, E);
    k_gather28<<<(N + 3) / 4, 256, 0, stream>>>(x, xbf, offs, pmeta, emsg, eps1, u28, N);
    k_mlp1<<<256, 512, 0, stream>>>(u28, w1p, m1b1, wts /*m1W2 frag*/, m1b2, h, stats, N);
    k_bn<<<2048, 256, 0, stream>>>(h, stats, bn1g, bn1b, invN, h, 0, N);

    // ---- layers 2..4 (node-range chunks) ----
    for (int l = 0; l < 3; ++l) {
        for (int c = 0; c < 2; ++c) {
            int n0 = (c == 0) ? 0 : NS;
            int n1 = (c == 0) ? NS : N;
            k_emsg<<<2048, 256, 0, stream>>>(pea4,
                beW1 + (size_t)l * 512, beb1 + (size_t)l * 128,
                wt_be(l), beb2 + (size_t)l * 128, emsg, offs, n0, n1);
            k_gather<<<(n1 - n0 + 3) / 4, 256, 0, stream>>>(h, offs, pmeta, emsg, a0,
                epsL, l, n0, n1);
        }
        k_mlp<<<256, 512, 0, stream>>>(a0, wt_m1(l), mb1 + (size_t)l * 128,
                                       wt_m2(l), mb2 + (size_t)l * 128, a0,
                                       stats + 256 * (l + 1), N);
        if (l < 2) {
            k_bn<<<2048, 256, 0, stream>>>(a0, stats + 256 * (l + 1),
                bng + (size_t)l * 128, bnb + (size_t)l * 128, invN, h, 1, N);
        }
    }

    // ---- pool with fused layer-4 BN+residual ----
    k_poolbn<<<(S + 3) / 4, 256, 0, stream>>>(a0, h, stats + 256 * 3,
        bng + 256, bnb + 256, invN, offs2, perm2, (float*)d_out, S);
}

// Round 12
// 999.978 us; speedup vs baseline: 1.2911x; 1.0273x over previous
//
#include <hip/hip_runtime.h>
#include <hip/hip_bf16.h>

// ZINC GINE inner, round 24 = r21 (verified best, 1002.6us) + prep1/prep28
// folded into k_prep (blocks 40/41, r16-proven) = -2 launches.
// r23 post-mortem: half-wave gather regressed (59us, FETCH +6MB from
// redundant h-row reads across halves). r22 coop fusion regressed (spills).
// r21 config: batch-of-4 zero-padded gather slots, stats folded into
// k_bn/k_poolbn, barrier-free wave-local k_emsg, 512-thr 2-barrier k_mlp.

#define BNEPS 1e-5f
#define LDA 136   // 128 + 8 shorts pad
#define SCAN_NB 240

typedef __attribute__((ext_vector_type(8))) short bf16x8;
typedef __attribute__((ext_vector_type(8))) unsigned short u16x8;
typedef __attribute__((ext_vector_type(4))) float f32x4;

__device__ inline short f2bf(float f) {
    __hip_bfloat16 h = __float2bfloat16(f);
    return *reinterpret_cast<short*>(&h);
}
__device__ inline unsigned short f2bfu(float f) {
    __hip_bfloat16 h = __float2bfloat16(f);
    return *reinterpret_cast<unsigned short*>(&h);
}
__device__ inline float bf2f(unsigned short u) {
    union { unsigned int i; float f; } v; v.i = ((unsigned int)u) << 16; return v.f;
}

// Fragment-ordered index for a [128][128] W^T (n = out col, k = in dim):
// frag (nt,kt) = ((n>>4)*4 + (k>>5)); lane = ((k>>3)&3)*16 + (n&15); j = k&7.
// Consumer: frag(nt,kt) for lane L is 16B at W[((nt*4+kt)*64 + L)*8].

// ---------------- prep: 10 weights frag-ordered + layer-1 W1 + edge W2 ----------------
__global__ __launch_bounds__(256) void k_prep(
    const float* __restrict__ m1W2, const float* __restrict__ beW2,
    const float* __restrict__ mW1, const float* __restrict__ mW2,
    const float* __restrict__ m1W1, const float* __restrict__ be1W2,
    short* __restrict__ out, short* __restrict__ out1, short* __restrict__ out28)
{
    __shared__ float tileS[64][65];
    int b = blockIdx.x;
    if (b == 40) {
        // layer-1 W1 [28,128] -> frag-ordered (8 nt frags, K padded 32)
        for (int i = threadIdx.x; i < 4096; i += 256) {
            int j = i & 7, sub = (i >> 3) & 63, nt = i >> 9;
            int quad = sub >> 4, l15 = sub & 15;
            int n = nt * 16 + l15, k = quad * 8 + j;
            out1[i] = (k < 28) ? f2bf(m1W1[(size_t)k * 128 + n]) : (short)0;
        }
        return;
    }
    if (b == 41) {
        // layer-1 edge W2 [28,28] -> bf16 W^T padded [32][32]
        for (int i = threadIdx.x; i < 32 * 32; i += 256) {
            int n = i >> 5, k = i & 31;
            out28[i] = (n < 28 && k < 28) ? f2bf(be1W2[(size_t)k * 28 + n]) : (short)0;
        }
        return;
    }
    int mat = b >> 2, t = b & 3;
    const float* Wsrc;
    if (mat == 0) Wsrc = m1W2;
    else {
        int l = (mat - 1) / 3, which = (mat - 1) % 3;
        Wsrc = (which == 0) ? beW2 + (size_t)l * 16384
             : (which == 1) ? mW1 + (size_t)l * 16384
             :                mW2 + (size_t)l * 16384;
    }
    short* dst = out + (size_t)mat * 16384;
    int tr = (t >> 1) * 64, tc = (t & 1) * 64;   // tr: k-range, tc: n-range
    for (int i = threadIdx.x; i < 4096; i += 256) {
        int r = i >> 6, c = i & 63;
        tileS[r][c] = Wsrc[(size_t)(tr + r) * 128 + (tc + c)];
    }
    __syncthreads();
    for (int i = threadIdx.x; i < 4096; i += 256) {
        int kl = i & 63, nl = i >> 6;
        int n = tc + nl, k = tr + kl;
        int fo = (((n >> 4) * 4 + (k >> 5)) * 64 + (((k >> 3) & 3) * 16 + (n & 15))) * 8 + (k & 7);
        dst[fo] = f2bf(tileS[kl][nl]);
    }
}

// ---------------- prep: x [N,28] f32 -> x_bf [N,32] bf16 ----------------
__global__ __launch_bounds__(256) void k_prepx(
    const float* __restrict__ x, unsigned short* __restrict__ xbf, int N)
{
    int total = N * 32;
    for (int i = blockIdx.x * 256 + threadIdx.x; i < total; i += gridDim.x * 256) {
        int n = i >> 5, c = i & 31;
        xbf[i] = (c < 28) ? f2bfu(x[(size_t)n * 28 + c]) : (unsigned short)0;
    }
}

// ---------------- CSR build ----------------
__global__ __launch_bounds__(256) void k_count(
    const int* __restrict__ ei, int* __restrict__ counts, int E)
{
    for (int e = blockIdx.x * 256 + threadIdx.x; e < E; e += gridDim.x * 256)
        atomicAdd(&counts[ei[E + e]], 1);
}

__global__ __launch_bounds__(256) void k_count2(
    const int* __restrict__ s2n, const float* __restrict__ mask,
    int* __restrict__ counts2, int N)
{
    for (int n = blockIdx.x * 256 + threadIdx.x; n < N; n += gridDim.x * 256)
        if (mask[n] != 0.f) atomicAdd(&counts2[s2n[n]], 1);
}

__global__ __launch_bounds__(256) void k_scanA(
    const int* __restrict__ counts, int* __restrict__ bsum, int N, int seg)
{
    __shared__ int red[256];
    int b = blockIdx.x;
    int lo = b * seg, hi = min(lo + seg, N);
    int s = 0;
    for (int i = lo + threadIdx.x; i < hi; i += 256) s += counts[i];
    red[threadIdx.x] = s;
    __syncthreads();
    for (int d = 128; d > 0; d >>= 1) {
        if (threadIdx.x < d) red[threadIdx.x] += red[threadIdx.x + d];
        __syncthreads();
    }
    if (threadIdx.x == 0) bsum[b] = red[0];
}

__global__ __launch_bounds__(256) void k_scanB(
    int* __restrict__ bsum, int nb, int* __restrict__ offs, int N)
{
    __shared__ int sh[256];
    int v = (threadIdx.x < nb) ? bsum[threadIdx.x] : 0;
    sh[threadIdx.x] = v;
    __syncthreads();
    for (int d = 1; d < 256; d <<= 1) {
        int t = (threadIdx.x >= d) ? sh[threadIdx.x - d] : 0;
        __syncthreads();
        sh[threadIdx.x] += t;
        __syncthreads();
    }
    if (threadIdx.x < nb) bsum[threadIdx.x] = sh[threadIdx.x] - v;
    if (threadIdx.x == 0) offs[N] = sh[255];
}

__global__ __launch_bounds__(256) void k_scanC(
    const int* __restrict__ counts, const int* __restrict__ bsum,
    int* __restrict__ offs, int* __restrict__ cursor, int N, int seg)
{
    __shared__ int sh[256];
    int b = blockIdx.x;
    int lo = b * seg, hi = min(lo + seg, N);
    int base = bsum[b];
    for (int t0 = lo; t0 < hi; t0 += 256) {
        int i = t0 + threadIdx.x;
        int v = (i < hi) ? counts[i] : 0;
        sh[threadIdx.x] = v;
        __syncthreads();
        for (int d = 1; d < 256; d <<= 1) {
            int t = (threadIdx.x >= d) ? sh[threadIdx.x - d] : 0;
            __syncthreads();
            sh[threadIdx.x] += t;
            __syncthreads();
        }
        int excl = base + sh[threadIdx.x] - v;
        if (i < hi) { offs[i] = excl; cursor[i] = excl; }
        int tileTotal = sh[255];
        __syncthreads();
        base += tileTotal;
    }
}

__global__ __launch_bounds__(256) void k_scatter(
    const int* __restrict__ ei, const float* __restrict__ ew,
    const float4* __restrict__ ea4,
    int* __restrict__ cursor, int2* __restrict__ pmeta,
    float4* __restrict__ pea4, int E)
{
    for (int e = blockIdx.x * 256 + threadIdx.x; e < E; e += gridDim.x * 256) {
        int d = ei[E + e];
        int pos = atomicAdd(&cursor[d], 1);
        pmeta[pos] = make_int2(ei[e], __float_as_int(ew[e]));
        pea4[pos] = ea4[e];
    }
}

__global__ __launch_bounds__(256) void k_scatter2(
    const int* __restrict__ s2n, const float* __restrict__ mask,
    int* __restrict__ cursor2, int* __restrict__ perm2, int N)
{
    for (int n = blockIdx.x * 256 + threadIdx.x; n < N; n += gridDim.x * 256)
        if (mask[n] != 0.f) {
            int pos = atomicAdd(&cursor2[s2n[n]], 1);
            perm2[pos] = n;
        }
}

// ---------------- hidden edge GEMM: barrier-free wave-local ----------------
__global__ __launch_bounds__(256, 3) void k_emsg(
    const float4* __restrict__ pea4,
    const float* __restrict__ W1, const float* __restrict__ b1,
    const short* __restrict__ W2f, const float* __restrict__ b2,
    unsigned short* __restrict__ emsg, const int* __restrict__ offs,
    int n0, int n1)
{
    __shared__ short As[64 * LDA];     // 17408 B
    __shared__ short Bs[16384];        // 32768 B  (frag-ordered W2)
    int e0 = offs[n0], e1 = offs[n1];
    int tid = threadIdx.x;
    int w = tid >> 6, lane = tid & 63;
    int l15 = lane & 15, quad = lane >> 4;
    int rb = w * 16;
    for (int i = tid; i < 2048; i += 256)
        *(bf16x8*)&Bs[i * 8] = *(const bf16x8*)&W2f[i * 8];
    int c2 = lane * 2;
    float w1a[4], w1b[4];
    #pragma unroll
    for (int a = 0; a < 4; ++a) { w1a[a] = W1[a * 128 + c2]; w1b[a] = W1[a * 128 + c2 + 1]; }
    float b1a = b1[c2], b1b = b1[c2 + 1];
    float b2r[8];
    #pragma unroll
    for (int nt = 0; nt < 8; ++nt) b2r[nt] = b2[nt * 16 + l15];
    __syncthreads();   // Bs ready (only barrier)

    const float* peaf = (const float*)pea4;
    int numTiles = (e1 - e0 + 63) >> 6;
    for (int tile = blockIdx.x; tile < numTiles; tile += gridDim.x) {
        int base = e0 + tile * 64;
        int eidx = base + rb + (lane >> 2);
        float v = (eidx < e1) ? peaf[(size_t)(base + rb) * 4 + lane] : 0.f;
        #pragma unroll
        for (int e = 0; e < 16; ++e) {
            float a0v = __shfl(v, e * 4 + 0);
            float a1v = __shfl(v, e * 4 + 1);
            float a2v = __shfl(v, e * 4 + 2);
            float a3v = __shfl(v, e * 4 + 3);
            float t0 = fmaf(a0v, w1a[0], fmaf(a1v, w1a[1], fmaf(a2v, w1a[2], fmaf(a3v, w1a[3], b1a))));
            float t1 = fmaf(a0v, w1b[0], fmaf(a1v, w1b[1], fmaf(a2v, w1b[2], fmaf(a3v, w1b[3], b1b))));
            unsigned int pk = ((unsigned int)f2bfu(fmaxf(t1, 0.f)) << 16) | f2bfu(fmaxf(t0, 0.f));
            *(unsigned int*)&As[(rb + e) * LDA + c2] = pk;
        }
        f32x4 acc[8];
        #pragma unroll
        for (int nt = 0; nt < 8; ++nt) acc[nt] = (f32x4){0.f, 0.f, 0.f, 0.f};
        #pragma unroll
        for (int kt = 0; kt < 4; ++kt) {
            bf16x8 af = *(bf16x8*)&As[(rb + l15) * LDA + kt * 32 + quad * 8];
            #pragma unroll
            for (int nt = 0; nt < 8; ++nt) {
                bf16x8 bf = *(const bf16x8*)&Bs[((nt * 4 + kt) * 64 + lane) * 8];
                acc[nt] = __builtin_amdgcn_mfma_f32_16x16x32_bf16(af, bf, acc[nt], 0, 0, 0);
            }
        }
        #pragma unroll
        for (int nt = 0; nt < 8; ++nt) {
            #pragma unroll
            for (int r = 0; r < 4; ++r)
                As[(rb + quad * 4 + r) * LDA + nt * 16 + l15] = f2bf(acc[nt][r] + b2r[nt]);
        }
        #pragma unroll
        for (int it = 0; it < 4; ++it) {
            int arow = rb + it * 4 + quad;
            int gr = base + arow;
            if (gr < e1)
                *(bf16x8*)&emsg[(size_t)(gr - e0) * 128 + l15 * 8] = *(bf16x8*)&As[arow * LDA + l15 * 8];
        }
    }
}

// ---------------- layer-1 edge MLP via MFMA (r13-style) ----------------
__global__ __launch_bounds__(256) void k_emsg28_mm(
    const float4* __restrict__ pea4,
    const float* __restrict__ W1, const float* __restrict__ b1,
    const short* __restrict__ W2t28,
    const float* __restrict__ b2,
    unsigned short* __restrict__ emsg28, int E)
{
    __shared__ short Bs[32 * 40];
    __shared__ short As[64 * 40];
    __shared__ float eas[64][4];
    __shared__ float b2s[32];
    int tid = threadIdx.x;
    for (int i = tid; i < 32 * 32; i += 256) {
        int n = i >> 5, k = i & 31;
        Bs[n * 40 + k] = W2t28[i];
    }
    if (tid < 32) b2s[tid] = (tid < 28) ? b2[tid] : 0.f;
    int j = tid & 31, sub = tid >> 5;
    float w10 = 0.f, w11 = 0.f, w12 = 0.f, w13 = 0.f, b1j = 0.f;
    if (j < 28) { w10 = W1[j]; w11 = W1[28 + j]; w12 = W1[56 + j]; w13 = W1[84 + j]; b1j = b1[j]; }
    int w = tid >> 6, lane = tid & 63;
    int l15 = lane & 15, quad = lane >> 4;
    __syncthreads();

    int numTiles = (E + 63) >> 6;
    for (int tile = blockIdx.x; tile < numTiles; tile += gridDim.x) {
        int base = tile * 64;
        __syncthreads();
        if (tid < 64) {
            int k = base + tid;
            float4 a = (k < E) ? pea4[k] : make_float4(0.f, 0.f, 0.f, 0.f);
            eas[tid][0] = a.x; eas[tid][1] = a.y; eas[tid][2] = a.z; eas[tid][3] = a.w;
        }
        __syncthreads();
        #pragma unroll
        for (int q = 0; q < 8; ++q) {
            int e = q * 8 + sub;
            float t = fmaf(eas[e][0], w10, fmaf(eas[e][1], w11,
                      fmaf(eas[e][2], w12, fmaf(eas[e][3], w13, b1j))));
            As[e * 40 + j] = (j < 28) ? f2bf(fmaxf(t, 0.f)) : (short)0;
        }
        __syncthreads();
        f32x4 acc[2];
        acc[0] = (f32x4){0.f, 0.f, 0.f, 0.f};
        acc[1] = (f32x4){0.f, 0.f, 0.f, 0.f};
        bf16x8 af = *(bf16x8*)&As[(w * 16 + l15) * 40 + quad * 8];
        #pragma unroll
        for (int nt = 0; nt < 2; ++nt) {
            bf16x8 bf = *(bf16x8*)&Bs[(nt * 16 + l15) * 40 + quad * 8];
            acc[nt] = __builtin_amdgcn_mfma_f32_16x16x32_bf16(af, bf, acc[nt], 0, 0, 0);
        }
        __syncthreads();
        #pragma unroll
        for (int nt = 0; nt < 2; ++nt) {
            int col = nt * 16 + l15;
            float bb = b2s[col];
            #pragma unroll
            for (int r = 0; r < 4; ++r)
                As[(w * 16 + quad * 4 + r) * 40 + col] = f2bf(acc[nt][r] + bb);
        }
        __syncthreads();
        for (int i = tid; i < 64 * 28; i += 256) {
            int row = i / 28, col = i - row * 28;
            int gr = base + row;
            if (gr < E) emsg28[(size_t)gr * 28 + col] = As[row * 40 + col];
        }
    }
}

// ---------------- gather node-chunk [n0,n1): batch-of-4 zero-padded slots ----------------
__global__ __launch_bounds__(256) void k_gather(
    const unsigned short* __restrict__ h, const int* __restrict__ offs,
    const int2* __restrict__ pmeta, const unsigned short* __restrict__ emsg,
    unsigned short* __restrict__ a0,
    const float* __restrict__ epsp, int epsIdx,
    int n0, int n1)
{
    int grp = threadIdx.x >> 5, lane = threadIdx.x & 31;
    int n = n0 + blockIdx.x * 8 + grp;
    if (n >= n1) return;
    int e0 = offs[n0];
    int k0 = offs[n], k1 = offs[n + 1];
    float s = 1.0f + epsp[epsIdx];
    ushort4 hv0 = *(const ushort4*)&h[(size_t)n * 128 + lane * 4];
    float m0 = s * bf2f(hv0.x), m1 = s * bf2f(hv0.y);
    float m2 = s * bf2f(hv0.z), m3 = s * bf2f(hv0.w);
    int2 mtA, mtB, mtC, mtD;
    ushort4 evA, hvA, evB, hvB, evC, hvC, evD, hvD;
    const ushort4 z4 = {0, 0, 0, 0};
    #define GSLOT(mt, ev, hv, kk) \
        if ((kk) < k1) { \
            mt = pmeta[kk]; \
            ev = *(const ushort4*)&emsg[(size_t)((kk) - e0) * 128 + lane * 4]; \
            hv = *(const ushort4*)&h[(size_t)mt.x * 128 + lane * 4]; \
        } else { mt = make_int2(0, 0); ev = z4; hv = z4; }
    #define GCONS(mt, ev, hv) { \
            float wv = __int_as_float(mt.y); \
            m0 += fmaxf(bf2f(hv.x) + bf2f(ev.x), 0.f) * wv; \
            m1 += fmaxf(bf2f(hv.y) + bf2f(ev.y), 0.f) * wv; \
            m2 += fmaxf(bf2f(hv.z) + bf2f(ev.z), 0.f) * wv; \
            m3 += fmaxf(bf2f(hv.w) + bf2f(ev.w), 0.f) * wv; }
    GSLOT(mtA, evA, hvA, k0)
    GSLOT(mtB, evB, hvB, k0 + 1)
    GSLOT(mtC, evC, hvC, k0 + 2)
    GSLOT(mtD, evD, hvD, k0 + 3)
    int k = k0;
    while (true) {
        GCONS(mtA, evA, hvA)
        GCONS(mtB, evB, hvB)
        GCONS(mtC, evC, hvC)
        GCONS(mtD, evD, hvD)
        k += 4;
        if (k >= k1) break;
        GSLOT(mtA, evA, hvA, k)
        GSLOT(mtB, evB, hvB, k + 1)
        GSLOT(mtC, evC, hvC, k + 2)
        GSLOT(mtD, evD, hvD, k + 3)
    }
    #undef GSLOT
    #undef GCONS
    ushort4 o;
    o.x = f2bfu(m0); o.y = f2bfu(m1); o.z = f2bfu(m2); o.w = f2bfu(m3);
    *(ushort4*)&a0[(size_t)n * 128 + lane * 4] = o;
}

// ---------------- gather (d=28): batch-of-4 zero-padded slots ----------------
__global__ __launch_bounds__(256) void k_gather28(
    const float* __restrict__ x, const unsigned short* __restrict__ xbf,
    const int* __restrict__ offs,
    const int2* __restrict__ pmeta, const unsigned short* __restrict__ emsg28,
    const float* __restrict__ eps1, float* __restrict__ u28, int N)
{
    int grp = threadIdx.x >> 5, lane = threadIdx.x & 31;
    int n = blockIdx.x * 8 + grp;
    if (n >= N || lane >= 28) return;
    float s = 1.0f + eps1[0];
    int k0 = offs[n], k1 = offs[n + 1];
    float m = 0.f;
    int2 mtA, mtB, mtC, mtD;
    unsigned short eA, xA, eB, xB, eC, xC, eD, xD;
    #define GSLOT28(mt, ee, xx, kk) \
        if ((kk) < k1) { \
            mt = pmeta[kk]; \
            ee = emsg28[(size_t)(kk) * 28 + lane]; \
            xx = xbf[(size_t)mt.x * 32 + lane]; \
        } else { mt = make_int2(0, 0); ee = 0; xx = 0; }
    #define GCONS28(mt, ee, xx) \
        m += fmaxf(bf2f(xx) + bf2f(ee), 0.f) * __int_as_float(mt.y);
    GSLOT28(mtA, eA, xA, k0)
    GSLOT28(mtB, eB, xB, k0 + 1)
    GSLOT28(mtC, eC, xC, k0 + 2)
    GSLOT28(mtD, eD, xD, k0 + 3)
    int k = k0;
    while (true) {
        GCONS28(mtA, eA, xA)
        GCONS28(mtB, eB, xB)
        GCONS28(mtC, eC, xC)
        GCONS28(mtD, eD, xD)
        k += 4;
        if (k >= k1) break;
        GSLOT28(mtA, eA, xA, k)
        GSLOT28(mtB, eB, xB, k + 1)
        GSLOT28(mtC, eC, xC, k + 2)
        GSLOT28(mtD, eD, xD, k + 3)
    }
    #undef GSLOT28
    #undef GCONS28
    u28[(size_t)n * 28 + lane] = fmaf(s, x[(size_t)n * 28 + lane], m);
}

// ---------------- fused node MLP (hidden): 8 waves x 32 rows, 256-row tiles ----------------
__global__ __launch_bounds__(512, 2) void k_mlp(
    const unsigned short* __restrict__ src, const short* __restrict__ W1f,
    const float* __restrict__ b1, const short* __restrict__ W2f,
    const float* __restrict__ b2, unsigned short* __restrict__ dst,
    float* __restrict__ stats, int N)
{
    __shared__ short As[256 * LDA];    // 69632 B
    __shared__ short Bs1[16384];       // 32768 B
    __shared__ short Bs2[16384];       // 32768 B
    __shared__ float sstat[256];
    int tid = threadIdx.x;
    for (int i = tid; i < 2048; i += 512) {
        *(bf16x8*)&Bs1[i * 8] = *(const bf16x8*)&W1f[i * 8];
        *(bf16x8*)&Bs2[i * 8] = *(const bf16x8*)&W2f[i * 8];
    }
    if (tid < 256) sstat[tid] = 0.f;
    int w = tid >> 6, lane = tid & 63;
    int l15 = lane & 15, quad = lane >> 4;
    int rb = w * 32;
    float b1r[8], b2r[8], lsum[8], lsq[8];
    #pragma unroll
    for (int nt = 0; nt < 8; ++nt) {
        b1r[nt] = b1[nt * 16 + l15]; b2r[nt] = b2[nt * 16 + l15];
        lsum[nt] = 0.f; lsq[nt] = 0.f;
    }
    int numTiles = (N + 255) >> 8;
    bf16x8 st[8];
    {
        int tile = blockIdx.x;
        if (tile < numTiles) {
            int base = tile * 256;
            #pragma unroll
            for (int kk = 0; kk < 8; ++kk) {
                int i = tid + kk * 512;
                int rr = base + (i >> 4);
                st[kk] = (rr < N) ? *(const bf16x8*)&src[(size_t)rr * 128 + (i & 15) * 8]
                                  : (bf16x8){0, 0, 0, 0, 0, 0, 0, 0};
            }
        }
    }
    __syncthreads();

    for (int tile = blockIdx.x; tile < numTiles; tile += gridDim.x) {
        int base = tile * 256;
        #pragma unroll
        for (int kk = 0; kk < 8; ++kk) {
            int i = tid + kk * 512;
            *(bf16x8*)&As[(i >> 4) * LDA + (i & 15) * 8] = st[kk];
        }
        int tnext = tile + gridDim.x;
        if (tnext < numTiles) {
            int bn = tnext * 256;
            #pragma unroll
            for (int kk = 0; kk < 8; ++kk) {
                int i = tid + kk * 512;
                int rr = bn + (i >> 4);
                st[kk] = (rr < N) ? *(const bf16x8*)&src[(size_t)rr * 128 + (i & 15) * 8]
                                  : (bf16x8){0, 0, 0, 0, 0, 0, 0, 0};
            }
        }
        __syncthreads();   // As staged
        f32x4 acc[2][8];
        #pragma unroll
        for (int rg = 0; rg < 2; ++rg)
            #pragma unroll
            for (int nt = 0; nt < 8; ++nt) acc[rg][nt] = (f32x4){0.f, 0.f, 0.f, 0.f};
        #pragma unroll
        for (int kt = 0; kt < 4; ++kt) {
            bf16x8 af0 = *(bf16x8*)&As[(rb + l15) * LDA + kt * 32 + quad * 8];
            bf16x8 af1 = *(bf16x8*)&As[(rb + 16 + l15) * LDA + kt * 32 + quad * 8];
            #pragma unroll
            for (int nt = 0; nt < 8; ++nt) {
                bf16x8 bf = *(const bf16x8*)&Bs1[((nt * 4 + kt) * 64 + lane) * 8];
                acc[0][nt] = __builtin_amdgcn_mfma_f32_16x16x32_bf16(af0, bf, acc[0][nt], 0, 0, 0);
                acc[1][nt] = __builtin_amdgcn_mfma_f32_16x16x32_bf16(af1, bf, acc[1][nt], 0, 0, 0);
            }
        }
        #pragma unroll
        for (int rg = 0; rg < 2; ++rg)
            #pragma unroll
            for (int nt = 0; nt < 8; ++nt)
                #pragma unroll
                for (int r = 0; r < 4; ++r)
                    As[(rb + rg * 16 + quad * 4 + r) * LDA + nt * 16 + l15] =
                        f2bf(fmaxf(acc[rg][nt][r] + b1r[nt], 0.f));
        #pragma unroll
        for (int rg = 0; rg < 2; ++rg)
            #pragma unroll
            for (int nt = 0; nt < 8; ++nt) acc[rg][nt] = (f32x4){0.f, 0.f, 0.f, 0.f};
        #pragma unroll
        for (int kt = 0; kt < 4; ++kt) {
            bf16x8 af0 = *(bf16x8*)&As[(rb + l15) * LDA + kt * 32 + quad * 8];
            bf16x8 af1 = *(bf16x8*)&As[(rb + 16 + l15) * LDA + kt * 32 + quad * 8];
            #pragma unroll
            for (int nt = 0; nt < 8; ++nt) {
                bf16x8 bf = *(const bf16x8*)&Bs2[((nt * 4 + kt) * 64 + lane) * 8];
                acc[0][nt] = __builtin_amdgcn_mfma_f32_16x16x32_bf16(af0, bf, acc[0][nt], 0, 0, 0);
                acc[1][nt] = __builtin_amdgcn_mfma_f32_16x16x32_bf16(af1, bf, acc[1][nt], 0, 0, 0);
            }
        }
        #pragma unroll
        for (int rg = 0; rg < 2; ++rg)
            #pragma unroll
            for (int nt = 0; nt < 8; ++nt) {
                int row0 = base + rb + rg * 16 + quad * 4;
                #pragma unroll
                for (int r = 0; r < 4; ++r) {
                    float z = acc[rg][nt][r] + b2r[nt];
                    if (row0 + r < N) { lsum[nt] += z; lsq[nt] = fmaf(z, z, lsq[nt]); }
                    As[(rb + rg * 16 + quad * 4 + r) * LDA + nt * 16 + l15] = f2bf(z);
                }
            }
        #pragma unroll
        for (int it = 0; it < 8; ++it) {
            int arow = rb + it * 4 + quad;
            int rr = base + arow;
            if (rr < N)
                *(bf16x8*)&dst[(size_t)rr * 128 + l15 * 8] = *(bf16x8*)&As[arow * LDA + l15 * 8];
        }
        __syncthreads();   // all As reads done before next stage-write
    }
    #pragma unroll
    for (int nt = 0; nt < 8; ++nt) {
        atomicAdd(&sstat[nt * 16 + l15], lsum[nt]);
        atomicAdd(&sstat[128 + nt * 16 + l15], lsq[nt]);
    }
    __syncthreads();
    if (tid < 256) atomicAdd(&stats[tid], sstat[tid]);
}

// ---------------- fused layer-1 node MLP ----------------
__global__ __launch_bounds__(512, 2) void k_mlp1(
    const float* __restrict__ u28, const short* __restrict__ W1f,
    const float* __restrict__ b1, const short* __restrict__ W2f,
    const float* __restrict__ b2, unsigned short* __restrict__ dst,
    float* __restrict__ stats, int N)
{
    __shared__ short A28[256 * 40];    // 20480 B
    __shared__ short As[256 * LDA];    // 69632 B
    __shared__ short Bs1[4096];        // 8192 B (frag-ordered, K padded 32)
    __shared__ short Bs2[16384];       // 32768 B
    __shared__ float sstat[256];
    int tid = threadIdx.x;
    if (tid < 512) {
        int i = tid;
        *(bf16x8*)&Bs1[i * 8] = *(const bf16x8*)&W1f[i * 8];
    }
    for (int i = tid; i < 2048; i += 512)
        *(bf16x8*)&Bs2[i * 8] = *(const bf16x8*)&W2f[i * 8];
    for (int i = tid; i < 1024; i += 512) {
        int row = i >> 2, c = 28 + (i & 3);
        A28[row * 40 + c] = 0;
    }
    if (tid < 256) sstat[tid] = 0.f;
    int w = tid >> 6, lane = tid & 63;
    int l15 = lane & 15, quad = lane >> 4;
    int rb = w * 32;
    float b1r[8], b2r[8], lsum[8], lsq[8];
    #pragma unroll
    for (int nt = 0; nt < 8; ++nt) {
        b1r[nt] = b1[nt * 16 + l15]; b2r[nt] = b2[nt * 16 + l15];
        lsum[nt] = 0.f; lsq[nt] = 0.f;
    }
    int numTiles = (N + 255) >> 8;
    float stf[14];
    {
        int tile = blockIdx.x;
        if (tile < numTiles) {
            int base = tile * 256;
            #pragma unroll
            for (int kk = 0; kk < 14; ++kk) {
                int idx = tid + kk * 512;
                int row = idx / 28, col = idx - row * 28;
                int rr = base + row;
                stf[kk] = (rr < N) ? u28[(size_t)rr * 28 + col] : 0.f;
            }
        }
    }
    __syncthreads();

    for (int tile = blockIdx.x; tile < numTiles; tile += gridDim.x) {
        int base = tile * 256;
        #pragma unroll
        for (int kk = 0; kk < 14; ++kk) {
            int idx = tid + kk * 512;
            int row = idx / 28, col = idx - row * 28;
            A28[row * 40 + col] = f2bf(stf[kk]);
        }
        int tnext = tile + gridDim.x;
        if (tnext < numTiles) {
            int bn = tnext * 256;
            #pragma unroll
            for (int kk = 0; kk < 14; ++kk) {
                int idx = tid + kk * 512;
                int row = idx / 28, col = idx - row * 28;
                int rr = bn + row;
                stf[kk] = (rr < N) ? u28[(size_t)rr * 28 + col] : 0.f;
            }
        }
        __syncthreads();   // A28 staged
        f32x4 acc[2][8];
        #pragma unroll
        for (int rg = 0; rg < 2; ++rg)
            #pragma unroll
            for (int nt = 0; nt < 8; ++nt) acc[rg][nt] = (f32x4){0.f, 0.f, 0.f, 0.f};
        {
            bf16x8 af0 = *(bf16x8*)&A28[(rb + l15) * 40 + quad * 8];
            bf16x8 af1 = *(bf16x8*)&A28[(rb + 16 + l15) * 40 + quad * 8];
            #pragma unroll
            for (int nt = 0; nt < 8; ++nt) {
                bf16x8 bf = *(const bf16x8*)&Bs1[(nt * 64 + lane) * 8];
                acc[0][nt] = __builtin_amdgcn_mfma_f32_16x16x32_bf16(af0, bf, acc[0][nt], 0, 0, 0);
                acc[1][nt] = __builtin_amdgcn_mfma_f32_16x16x32_bf16(af1, bf, acc[1][nt], 0, 0, 0);
            }
        }
        #pragma unroll
        for (int rg = 0; rg < 2; ++rg)
            #pragma unroll
            for (int nt = 0; nt < 8; ++nt)
                #pragma unroll
                for (int r = 0; r < 4; ++r)
                    As[(rb + rg * 16 + quad * 4 + r) * LDA + nt * 16 + l15] =
                        f2bf(fmaxf(acc[rg][nt][r] + b1r[nt], 0.f));
        __syncthreads();
        #pragma unroll
        for (int rg = 0; rg < 2; ++rg)
            #pragma unroll
            for (int nt = 0; nt < 8; ++nt) acc[rg][nt] = (f32x4){0.f, 0.f, 0.f, 0.f};
        #pragma unroll
        for (int kt = 0; kt < 4; ++kt) {
            bf16x8 af0 = *(bf16x8*)&As[(rb + l15) * LDA + kt * 32 + quad * 8];
            bf16x8 af1 = *(bf16x8*)&As[(rb + 16 + l15) * LDA + kt * 32 + quad * 8];
            #pragma unroll
            for (int nt = 0; nt < 8; ++nt) {
                bf16x8 bf = *(const bf16x8*)&Bs2[((nt * 4 + kt) * 64 + lane) * 8];
                acc[0][nt] = __builtin_amdgcn_mfma_f32_16x16x32_bf16(af0, bf, acc[0][nt], 0, 0, 0);
                acc[1][nt] = __builtin_amdgcn_mfma_f32_16x16x32_bf16(af1, bf, acc[1][nt], 0, 0, 0);
            }
        }
        #pragma unroll
        for (int rg = 0; rg < 2; ++rg)
            #pragma unroll
            for (int nt = 0; nt < 8; ++nt) {
                int row0 = base + rb + rg * 16 + quad * 4;
                #pragma unroll
                for (int r = 0; r < 4; ++r) {
                    float z = acc[rg][nt][r] + b2r[nt];
                    if (row0 + r < N) { lsum[nt] += z; lsq[nt] = fmaf(z, z, lsq[nt]); }
                    As[(rb + rg * 16 + quad * 4 + r) * LDA + nt * 16 + l15] = f2bf(z);
                }
            }
        #pragma unroll
        for (int it = 0; it < 8; ++it) {
            int arow = rb + it * 4 + quad;
            int rr = base + arow;
            if (rr < N)
                *(bf16x8*)&dst[(size_t)rr * 128 + l15 * 8] = *(bf16x8*)&As[arow * LDA + l15 * 8];
        }
        __syncthreads();
    }
    #pragma unroll
    for (int nt = 0; nt < 8; ++nt) {
        atomicAdd(&sstat[nt * 16 + l15], lsum[nt]);
        atomicAdd(&sstat[128 + nt * 16 + l15], lsq[nt]);
    }
    __syncthreads();
    if (tid < 256) atomicAdd(&stats[tid], sstat[tid]);
}

// ---------------- BN-apply+relu(+residual), stats folded in ----------------
__global__ __launch_bounds__(256) void k_bn(
    const unsigned short* __restrict__ z, const float* __restrict__ stats,
    const float* __restrict__ g, const float* __restrict__ bb, float invN,
    unsigned short* __restrict__ h, int residual, int N)
{
    __shared__ float ss[256];
    if (threadIdx.x < 128) {
        int j = threadIdx.x;
        float mu  = stats[j] * invN;
        float var = fmaf(stats[128 + j], invN, -mu * mu);
        float sc  = rsqrtf(fmaxf(var, 0.f) + BNEPS) * g[j];
        ss[j] = sc;
        ss[128 + j] = fmaf(-mu, sc, bb[j]);
    }
    __syncthreads();
    int idx8 = blockIdx.x * 256 + threadIdx.x;
    int stride = gridDim.x * 256;
    int c0 = (idx8 & 15) * 8;
    float scl[8], sht[8];
    #pragma unroll
    for (int r = 0; r < 8; ++r) { scl[r] = ss[c0 + r]; sht[r] = ss[128 + c0 + r]; }
    int total8 = N * 16;
    for (; idx8 < total8; idx8 += stride) {
        int n = idx8 >> 4;
        u16x8 z8 = *(const u16x8*)&z[(size_t)n * 128 + c0];
        float hn[8];
        #pragma unroll
        for (int r = 0; r < 8; ++r)
            hn[r] = fmaxf(fmaf(bf2f(z8[r]), scl[r], sht[r]), 0.f);
        if (residual) {
            u16x8 h8 = *(const u16x8*)&h[(size_t)n * 128 + c0];
            #pragma unroll
            for (int r = 0; r < 8; ++r) hn[r] += bf2f(h8[r]);
        }
        u16x8 o;
        #pragma unroll
        for (int r = 0; r < 8; ++r) o[r] = f2bfu(hn[r]);
        *(u16x8*)&h[(size_t)n * 128 + c0] = o;
    }
}

// ---------------- pool with fused last-layer BN+residual, stats folded in ----------------
__global__ __launch_bounds__(256) void k_poolbn(
    const unsigned short* __restrict__ z, const unsigned short* __restrict__ hprev,
    const float* __restrict__ stats, const float* __restrict__ g,
    const float* __restrict__ bb, float invN,
    const int* __restrict__ offs2, const int* __restrict__ perm2,
    float* __restrict__ out, int S)
{
    __shared__ float ss[256];
    if (threadIdx.x < 128) {
        int j = threadIdx.x;
        float mu  = stats[j] * invN;
        float var = fmaf(stats[128 + j], invN, -mu * mu);
        float sc  = rsqrtf(fmaxf(var, 0.f) + BNEPS) * g[j];
        ss[j] = sc;
        ss[128 + j] = fmaf(-mu, sc, bb[j]);
    }
    __syncthreads();
    int w = threadIdx.x >> 6, lane = threadIdx.x & 63;
    int s = blockIdx.x * 4 + w;
    if (s >= S) return;
    int c0 = lane * 2;
    float scl0 = ss[c0], scl1 = ss[c0 + 1];
    float sht0 = ss[128 + c0], sht1 = ss[128 + c0 + 1];
    int k0 = offs2[s], k1 = offs2[s + 1];
    float a0 = 0.f, a1 = 0.f;
    for (int k = k0; k < k1; ++k) {
        int n = perm2[k];
        ushort2 zv = *(const ushort2*)&z[(size_t)n * 128 + c0];
        ushort2 hv = *(const ushort2*)&hprev[(size_t)n * 128 + c0];
        a0 += fmaxf(fmaf(bf2f(zv.x), scl0, sht0), 0.f) + bf2f(hv.x);
        a1 += fmaxf(fmaf(bf2f(zv.y), scl1, sht1), 0.f) + bf2f(hv.y);
    }
    *(float2*)&out[(size_t)s * 128 + c0] = make_float2(a0, a1);
}

extern "C" void kernel_launch(void* const* d_in, const int* in_sizes, int n_in,
                              void* d_out, int out_size, void* d_ws, size_t ws_size,
                              hipStream_t stream) {
    const float* x    = (const float*)d_in[0];
    const int*   ei   = (const int*)d_in[1];
    const float* ea   = (const float*)d_in[2];
    const float* ew   = (const float*)d_in[3];
    const float* mask = (const float*)d_in[4];
    const int*   s2n  = (const int*)d_in[5];
    const float* be1W1 = (const float*)d_in[6];
    const float* be1b1 = (const float*)d_in[7];
    const float* be1W2 = (const float*)d_in[8];
    const float* be1b2 = (const float*)d_in[9];
    const float* m1W1  = (const float*)d_in[10];
    const float* m1b1  = (const float*)d_in[11];
    const float* m1W2  = (const float*)d_in[12];
    const float* m1b2  = (const float*)d_in[13];
    const float* bn1g  = (const float*)d_in[14];
    const float* bn1b  = (const float*)d_in[15];
    const float* eps1  = (const float*)d_in[16];
    const float* beW1  = (const float*)d_in[17];
    const float* beb1  = (const float*)d_in[18];
    const float* beW2  = (const float*)d_in[19];
    const float* beb2  = (const float*)d_in[20];
    const float* mW1   = (const float*)d_in[21];
    const float* mb1   = (const float*)d_in[22];
    const float* mW2   = (const float*)d_in[23];
    const float* mb2   = (const float*)d_in[24];
    const float* bng   = (const float*)d_in[25];
    const float* bnb   = (const float*)d_in[26];
    const float* epsL  = (const float*)d_in[27];

    const int N = in_sizes[0] / 28;
    const int E = in_sizes[1] / 2;
    const int S = out_size / 128;
    const float invN = 1.0f / (float)N;
    const int NS = N / 2;
    const int EMC = E / 2 + 8192;

    auto al16 = [](size_t v) { return (v + 15) & ~(size_t)15; };
    char* ws = (char*)d_ws;
    size_t offH      = 0;
    size_t offA0     = al16(offH + (size_t)N * 256);
    size_t offEm     = al16(offA0 + (size_t)N * 256);
    size_t emBytes   = (size_t)EMC * 256;
    if ((size_t)E * 56 > emBytes) emBytes = (size_t)E * 56;
    size_t offStats  = al16(offEm + emBytes);
    size_t offSS     = al16(offStats + 4096);
    size_t offWts    = al16(offSS + 1024);
    size_t offCounts = al16(offWts + 10 * 16384 * 2 + 4096 * 2 + 1024 * 2);
    size_t offOffs   = al16(offCounts + (size_t)N * 4);
    size_t offCursor = al16(offOffs + (size_t)(N + 1) * 4);
    size_t offPmeta  = al16(offCursor + (size_t)N * 4);
    size_t offPea    = al16(offPmeta + (size_t)E * 8);
    size_t offBsum   = al16(offPea + (size_t)E * 16);
    size_t offCnt2   = al16(offBsum + SCAN_NB * 4);
    size_t offOffs2  = al16(offCnt2 + (size_t)S * 4);
    size_t offCur2   = al16(offOffs2 + (size_t)(S + 1) * 4);
    size_t offPerm2  = al16(offCur2 + (size_t)S * 4);
    size_t need      = offPerm2 + (size_t)N * 4;
    if (ws_size < need) return;

    unsigned short* h    = (unsigned short*)(ws + offH);
    unsigned short* a0   = (unsigned short*)(ws + offA0);
    unsigned short* emsg = (unsigned short*)(ws + offEm);
    float* u28    = (float*)(ws + offA0);
    unsigned short* xbf = (unsigned short*)(ws + offA0 + 26214400);
    float* stats  = (float*)(ws + offStats);
    short* wts    = (short*)(ws + offWts);
    short* w1p    = wts + 10 * 16384;
    short* w2p28  = w1p + 4096;
    int*   counts = (int*)(ws + offCounts);
    int*   offs   = (int*)(ws + offOffs);
    int*   cursor = (int*)(ws + offCursor);
    int2*  pmeta  = (int2*)(ws + offPmeta);
    float4* pea4  = (float4*)(ws + offPea);
    int*   bsum   = (int*)(ws + offBsum);
    int*   cnt2   = (int*)(ws + offCnt2);
    int*   offs2  = (int*)(ws + offOffs2);
    int*   cur2   = (int*)(ws + offCur2);
    int*   perm2  = (int*)(ws + offPerm2);
    const float4* ea4 = (const float4*)ea;

    hipMemsetAsync(stats, 0, 4 * 256 * sizeof(float), stream);
    hipMemsetAsync(counts, 0, (size_t)N * sizeof(int), stream);
    hipMemsetAsync(cnt2, 0, (size_t)S * sizeof(int), stream);

    k_prep<<<42, 256, 0, stream>>>(m1W2, beW2, mW1, mW2, m1W1, be1W2, wts, w1p, w2p28);
    k_prepx<<<512, 256, 0, stream>>>(x, xbf, N);

    // ---- edge CSR (dst-sorted; attrs pre-permuted) ----
    const int seg = (N + SCAN_NB - 1) / SCAN_NB;
    k_count<<<1024, 256, 0, stream>>>(ei, counts, E);
    k_scanA<<<SCAN_NB, 256, 0, stream>>>(counts, bsum, N, seg);
    k_scanB<<<1, 256, 0, stream>>>(bsum, SCAN_NB, offs, N);
    k_scanC<<<SCAN_NB, 256, 0, stream>>>(counts, bsum, offs, cursor, N, seg);
    k_scatter<<<1024, 256, 0, stream>>>(ei, ew, ea4, cursor, pmeta, pea4, E);

    // ---- segment CSR ----
    const int seg2 = (S + SCAN_NB - 1) / SCAN_NB;
    k_count2<<<512, 256, 0, stream>>>(s2n, mask, cnt2, N);
    k_scanA<<<SCAN_NB, 256, 0, stream>>>(cnt2, bsum, S, seg2);
    k_scanB<<<1, 256, 0, stream>>>(bsum, SCAN_NB, offs2, S);
    k_scanC<<<SCAN_NB, 256, 0, stream>>>(cnt2, bsum, offs2, cur2, S, seg2);
    k_scatter2<<<512, 256, 0, stream>>>(s2n, mask, cur2, perm2, N);

    auto wt_be = [&](int l) { return wts + (size_t)(1 + 3 * l + 0) * 16384; };
    auto wt_m1 = [&](int l) { return wts + (size_t)(1 + 3 * l + 1) * 16384; };
    auto wt_m2 = [&](int l) { return wts + (size_t)(1 + 3 * l + 2) * 16384; };

    // ---- layer 1 (28 -> 128) ----
    k_emsg28_mm<<<2048, 256, 0, stream>>>(pea4, be1W1, be1b1, w2p28, be1b2, emsg, E);
    k_gather28<<<(N + 7) / 8, 256, 0, stream>>>(x, xbf, offs, pmeta, emsg, eps1, u28, N);
    k_mlp1<<<256, 512, 0, stream>>>(u28, w1p, m1b1, wts /*m1W2 frag*/, m1b2, h, stats, N);
    k_bn<<<2048, 256, 0, stream>>>(h, stats, bn1g, bn1b, invN, h, 0, N);

    // ---- layers 2..4 (node-range chunks) ----
    for (int l = 0; l < 3; ++l) {
        for (int c = 0; c < 2; ++c) {
            int n0 = (c == 0) ? 0 : NS;
            int n1 = (c == 0) ? NS : N;
            k_emsg<<<2048, 256, 0, stream>>>(pea4,
                beW1 + (size_t)l * 512, beb1 + (size_t)l * 128,
                wt_be(l), beb2 + (size_t)l * 128, emsg, offs, n0, n1);
            k_gather<<<(n1 - n0 + 7) / 8, 256, 0, stream>>>(h, offs, pmeta, emsg, a0,
                epsL, l, n0, n1);
        }
        k_mlp<<<256, 512, 0, stream>>>(a0, wt_m1(l), mb1 + (size_t)l * 128,
                                       wt_m2(l), mb2 + (size_t)l * 128, a0,
                                       stats + 256 * (l + 1), N);
        if (l < 2) {
            k_bn<<<2048, 256, 0, stream>>>(a0, stats + 256 * (l + 1),
                bng + (size_t)l * 128, bnb + (size_t)l * 128, invN, h, 1, N);
        }
    }

    // ---- pool with fused layer-4 BN+residual ----
    k_poolbn<<<(S + 3) / 4, 256, 0, stream>>>(a0, h, stats + 256 * 3,
        bng + 256, bnb + 256, invN, offs2, perm2, (float*)d_out, S);
}